// Round 9
// baseline (463.486 us; speedup 1.0000x reference)
//
#include <hip/hip_runtime.h>
#include <hip/hip_fp16.h>

#define NT 25
#define NXY 448
#define NPIX (448*448)
#define PXY 115
#define SXY 111

#define TW 32
#define TH 8
#define CH 5          // output frames per time-chunk == k_final chunk size (aligned!)
#define NZ 5          // number of time chunks (NT/CH)
#define GSL 8         // gram spatial slices

// complex MAC, all-fp16 packed (v_pk_fma_f16):
// z=(zr,zi), x=(xr,xi), w=(wr,wi)  (each one VGPR/SGPR holding 2xfp16)
//  pk1: (zr,zi) += (xr,xr)*(wr,wi)
//  pk2: (zr,zi) += (xi,xi)*(-wi,wr)
// weight is wave-uniform -> SGPR source (legal: 1 sgpr read per VOP3P instr)
#define CMACH(z, x, w)                                                                             \
    asm("v_pk_fma_f16 %0, %1, %2, %0 op_sel:[0,0,0] op_sel_hi:[0,1,1]"                             \
        : "+v"(z) : "v"(x), "s"(w));                                                               \
    asm("v_pk_fma_f16 %0, %1, %2, %0 op_sel:[1,1,0] op_sel_hi:[1,0,1] neg_lo:[0,1,0]"              \
        : "+v"(z) : "v"(x), "s"(w));

#define PKRELU(d, a)                                                                               \
    asm("v_pk_max_f16 %0, %1, 0" : "=v"(d) : "v"(a))

static __device__ __forceinline__ unsigned int packh2f(float lo, float hi) {
    auto h = __builtin_amdgcn_cvt_pkrtz(lo, hi);   // v_cvt_pkrtz_f16_f32
    return __builtin_bit_cast(unsigned int, h);
}

// ---------------- K1: gram partials (gid<640) + weight/bias fp16 packing (gid>=640)
// gram reads ONLY raw inputs -> can run before the conv kernel; its gP feeds k_post,
// whose gA feeds the fused final-epilogue in k_work.
__global__ __launch_bounds__(256) void k_pre(
    const float* __restrict__ re, const float* __restrict__ im,
    const float* __restrict__ w1r, const float* __restrict__ w1i,
    const float* __restrict__ w2r, const float* __restrict__ w2i,
    const float* __restrict__ b1r, const float* __restrict__ b1i,
    const float* __restrict__ b2r, const float* __restrict__ b2i,
    unsigned int* __restrict__ wt1h, unsigned int* __restrict__ wt2h,
    unsigned int* __restrict__ wbh, float* __restrict__ gP)
{
    const int gid = blockIdx.x;
    const int tid = threadIdx.x;

    if (gid >= 640) {
        // ---- weight packing path (8 blocks cover 2048 items) ----
        int i = (gid - 640) * 256 + tid;
        auto pk = [](float a, float b) {
            unsigned short ua = __half_as_ushort(__float2half_rn(a));
            unsigned short ub = __half_as_ushort(__float2half_rn(b));
            return (unsigned int)ua | ((unsigned int)ub << 16);
        };
        if (i < 300) {
            int c = i / 25, tap = i - c * 25;
            wt1h[tap*12 + c] = pk(w1r[i], w1i[i]);
        }
        if (i < 432) {
            int dt = i % 3; int t = i / 3; int c1 = t % 12; int c2 = t / 12;
            wt2h[(c1*3+dt)*12 + c2] = pk(w2r[i], w2i[i]);
        }
        if (i < 12)      wbh[i] = pk(b1r[i], b1i[i]);
        else if (i < 24) wbh[i] = pk(b2r[i-12], b2i[i-12]);
        return;
    }

    // ---- gram path ----
    __shared__ float s_red[4][50];
    const int b = gid >> 3;              // 0..79 = chunk*16 + i*4 + j
    const int slice = gid & 7;
    const int chunk = b >> 4;
    const int pidx = b & 15;
    const int X0 = (pidx >> 2) * SXY;
    const int Y0 = (pidx & 3) * SXY;

    float acc[50];
    #pragma unroll
    for (int k = 0; k < 50; ++k) acc[k] = 0.f;

    const int npx = PXY * PXY;           // 13225
    for (int pi = slice*256 + tid; pi < npx; pi += 256*GSL) {
        int px = pi / PXY, py = pi % PXY;
        size_t base = (size_t)(X0 + px) * NXY + (Y0 + py);
        float xr[5], xi[5];
        #pragma unroll
        for (int r = 0; r < 5; ++r) {
            size_t a = (size_t)(chunk*5 + r) * NPIX + base;
            xr[r] = re[a]; xi[r] = im[a];
        }
        #pragma unroll
        for (int t1 = 0; t1 < 5; ++t1)
            #pragma unroll
            for (int t2 = 0; t2 < 5; ++t2) {
                acc[(t1*5+t2)*2]   += xr[t1]*xr[t2] + xi[t1]*xi[t2];
                acc[(t1*5+t2)*2+1] += xi[t1]*xr[t2] - xr[t1]*xi[t2];
            }
    }
    #pragma unroll
    for (int k = 0; k < 50; ++k) {
        float v = acc[k];
        for (int m = 32; m > 0; m >>= 1) v += __shfl_xor(v, m, 64);
        acc[k] = v;
    }
    int lane = tid & 63, wid = tid >> 6;
    if (lane == 0) {
        #pragma unroll
        for (int k = 0; k < 50; ++k) s_red[wid][k] = acc[k];
    }
    __syncthreads();
    if (tid < 50) {
        gP[(b*GSL + slice)*50 + tid] =
            s_red[0][tid] + s_red[1][tid] + s_red[2][tid] + s_red[3][tid];
    }
}

// ---------------- K2: fold Gram partials -> Jacobi eig -> W (LDS) -> region-avg gA
__global__ __launch_bounds__(128) void k_post(
    const float* __restrict__ gP, const float* __restrict__ thres,
    float* __restrict__ gA)
{
    __shared__ float sW[80*50];
    const int tid = threadIdx.x;
    if (tid < 80) {
        const int b = tid;
        float Ar[5][5], Ai[5][5], Vr[5][5], Vi[5][5];
        #pragma unroll
        for (int a = 0; a < 5; ++a)
            #pragma unroll
            for (int c = 0; c < 5; ++c) {
                float sr = 0.f, si = 0.f;
                #pragma unroll
                for (int sl = 0; sl < GSL; ++sl) {
                    sr += gP[(b*GSL + sl)*50 + (a*5+c)*2];
                    si += gP[(b*GSL + sl)*50 + (a*5+c)*2 + 1];
                }
                Ar[a][c] = sr; Ai[a][c] = si;
                Vr[a][c] = (a==c) ? 1.f : 0.f;
                Vi[a][c] = 0.f;
            }
        for (int sw = 0; sw < 9; ++sw) {
            #pragma unroll
            for (int p = 0; p < 4; ++p) {
                #pragma unroll
                for (int q = p+1; q < 5; ++q) {
                    float apr = Ar[p][q], api = Ai[p][q];
                    float n2 = apr*apr + api*api;
                    if (n2 > 1e-24f) {
                        float mlen = sqrtf(n2);
                        float phr = apr / mlen, phi = api / mlen;
                        float tau = (Ar[q][q] - Ar[p][p]) / (2.f * mlen);
                        float tt = (tau >= 0.f ? 1.f : -1.f) / (fabsf(tau) + sqrtf(1.f + tau*tau));
                        float cc = 1.f / sqrtf(1.f + tt*tt);
                        float ss = tt * cc;
                        float wr2 = ss * phr, wi2 = ss * phi;
                        #pragma unroll
                        for (int k = 0; k < 5; ++k) {
                            float xr = Ar[k][p], xi2 = Ai[k][p];
                            float yr = Ar[k][q], yi = Ai[k][q];
                            Ar[k][p] = cc*xr - (wr2*yr + wi2*yi);
                            Ai[k][p] = cc*xi2 - (wr2*yi - wi2*yr);
                            Ar[k][q] = wr2*xr - wi2*xi2 + cc*yr;
                            Ai[k][q] = wr2*xi2 + wi2*xr + cc*yi;
                            float vxr = Vr[k][p], vxi = Vi[k][p];
                            float vyr = Vr[k][q], vyi = Vi[k][q];
                            Vr[k][p] = cc*vxr - (wr2*vyr + wi2*vyi);
                            Vi[k][p] = cc*vxi - (wr2*vyi - wi2*vyr);
                            Vr[k][q] = wr2*vxr - wi2*vxi + cc*vyr;
                            Vi[k][q] = wr2*vxi + wi2*vxr + cc*vyi;
                        }
                        #pragma unroll
                        for (int k = 0; k < 5; ++k) {
                            float xr = Ar[p][k], xi2 = Ai[p][k];
                            float yr = Ar[q][k], yi = Ai[q][k];
                            Ar[p][k] = cc*xr - (wr2*yr - wi2*yi);
                            Ai[p][k] = cc*xi2 - (wr2*yi + wi2*yr);
                            Ar[q][k] = wr2*xr + wi2*xi2 + cc*yr;
                            Ai[q][k] = wr2*xi2 - wi2*xr + cc*yi;
                        }
                    }
                }
            }
        }
        float sv[5], s0 = 0.f;
        #pragma unroll
        for (int k = 0; k < 5; ++k) { sv[k] = sqrtf(fmaxf(Ar[k][k], 0.f)); s0 = fmaxf(s0, sv[k]); }
        float th = fmaxf(thres[b], 0.f) * s0;
        float ratio[5];
        #pragma unroll
        for (int k = 0; k < 5; ++k)
            ratio[k] = sv[k] > 0.f ? fmaxf(sv[k] - th, 0.f) / sv[k] : 0.f;
        #pragma unroll
        for (int a = 0; a < 5; ++a)
            #pragma unroll
            for (int c = 0; c < 5; ++c) {
                float wr = 0.f, wi = 0.f;
                #pragma unroll
                for (int k = 0; k < 5; ++k) {
                    wr += ratio[k] * (Vr[a][k]*Vr[c][k] + Vi[a][k]*Vi[c][k]);
                    wi += ratio[k] * (Vi[a][k]*Vr[c][k] - Vr[a][k]*Vi[c][k]);
                }
                sW[b*50 + (a*5+c)*2]   = wr;
                sW[b*50 + (a*5+c)*2+1] = wi;
            }
    }
    __syncthreads();
    for (int it = tid; it < 245*25; it += 128) {
        int blk = it / 25, e = it % 25;
        int chunk = blk / 49;
        int rem = blk % 49;
        int rx = rem / 7, ry = rem % 7;
        int i0 = rx >> 1, i1 = (rx + 1) >> 1;
        int j0 = ry >> 1, j1 = (ry + 1) >> 1;
        float sr = 0.f, si = 0.f; int cnt = 0;
        for (int i = i0; i <= i1; ++i)
            for (int j = j0; j <= j1; ++j) {
                int b = chunk*16 + i*4 + j;
                sr += sW[b*50 + e*2];
                si += sW[b*50 + e*2 + 1];
                ++cnt;
            }
        float inv = 1.f / (float)cnt;
        gA[blk*50 + e*2]   = sr * inv;
        gA[blk*50 + e*2+1] = si * inv;
    }
}

// ---------------- K3: fused conv pipeline + final epilogue.
// conv1(1->12,5x5)+ReLU -> conv2(12->12,3t)+ReLU -> conv3(12->1) real
//   out = (x_re - dR*tsc)*pwv           (written per output frame)
// then block-end epilogue: out += Re(Wavg(z,region) . x5)*(1-p_w)  (was k_final).
// x5 = own-pixel (re,im) of the chunk's 5 frames, captured fp16 into LDS during
// the staging the kernel already does (time-chunks == k_final chunks).
// launch_bounds(256,4): r6/r7 post-mortem — tighter bounds force VGPR<=40 while the
// live set needs ~60 -> scratch spills. (256,4) = 64 VGPR, zero spill (r8: WRITE 29MB).
__global__ __launch_bounds__(256, 4) void k_work(
    const float* __restrict__ re, const float* __restrict__ im,
    const unsigned int* __restrict__ wt1h, const unsigned int* __restrict__ wt2h,
    const unsigned int* __restrict__ wbh,
    const float* __restrict__ w3r, const float* __restrict__ w3i,
    const float* __restrict__ b3r,
    const float* __restrict__ tau_w, const float* __restrict__ p_w,
    const int* __restrict__ num_iter,
    const float* __restrict__ gA,
    float* __restrict__ out)
{
    __shared__ unsigned int s_inv[2][12*36];   // double-buffered fp16 (re,im) input tile
    __shared__ unsigned int s_x5[CH][TH*TW];   // own-pixel fp16 (re,im), 5 chunk frames

    const int tid = threadIdx.x;
    const int tx = tid & 31;
    const int ty = tid >> 5;
    const int Y0 = blockIdx.x * TW;
    const int X0 = blockIdx.y * TH;
    const int z  = blockIdx.z;            // time chunk
    const int z0 = z * CH;                // first output frame of this chunk
    const int fs = (z == 0) ? 0 : z0 - 1; // first conv1 frame
    const int fe = (z0 + CH < NT) ? z0 + CH : NT - 1;  // last conv1 frame

    // wave-uniform params: uniform loads -> SGPRs
    float rw3[12], iw3[12];
    unsigned int ub1[12], ub2[12];
    #pragma unroll
    for (int c = 0; c < 12; ++c) {
        ub1[c] = wbh[c];
        ub2[c] = wbh[12 + c];
        rw3[c] = w3r[c]; iw3[c] = w3i[c];
    }
    const float b3v = b3r[0];
    const float pw_raw = p_w[0];
    const float tsc = fmaxf(tau_w[0], 0.f) / (float)num_iter[0];
    const float pwv = fmaxf(pw_raw, 0.f);
    const float qwv = 1.f - pw_raw;

    // staging geometry (frame-independent): item0 = tid, item1 = tid+256 (if < 432)
    const int idx1 = tid + 256;
    int r0 = tid / 36, c0 = tid - r0*36;
    int gx0 = X0 + r0 - 2, gy0 = Y0 + c0 - 2;
    bool k0 = (gx0 >= 0) && (gx0 < NXY) && (gy0 >= 0) && (gy0 < NXY);
    const int a0 = (k0 ? gx0 : 0) * NXY + (k0 ? gy0 : 0);
    const float m0 = k0 ? 1.f : 0.f;
    const bool ctr0 = (r0 >= 2) && (c0 >= 2) && (c0 < 34);        // r0<=7<10 always
    const int cadr0 = (r0-2)*TW + (c0-2);
    int r1 = idx1 / 36, c1_ = idx1 - r1*36;
    int gx1 = X0 + r1 - 2, gy1 = Y0 + c1_ - 2;
    bool k1 = (gx1 >= 0) && (gx1 < NXY) && (gy1 >= 0) && (gy1 < NXY);
    const int a1 = (k1 ? gx1 : 0) * NXY + (k1 ? gy1 : 0);
    const float m1 = k1 ? 1.f : 0.f;
    const bool ctr1 = (r1 < 10) && (c1_ >= 2) && (c1_ < 34);      // r1>=7>=2 always
    const int cadr1 = (r1-2)*TW + (c1_-2);

    // persistent h1 slots (relu'd fp16 pairs): hA=h[t-1], hB=h[t], hC=h[t+1]
    unsigned int hA[12], hB[12], hC[12];
    #pragma unroll
    for (int c = 0; c < 12; ++c) { hA[c] = 0u; hB[c] = 0u; hC[c] = 0u; }

    // conv1 for frame tf -> relu (packed) -> hs
    auto conv1_to = [&](int tf, unsigned int (&hs)[12]) {
        unsigned int a[12];
        #pragma unroll
        for (int c = 0; c < 12; ++c) a[c] = ub1[c];
        const unsigned int* sin_ = s_inv[tf & 1];
        #pragma unroll 1
        for (int ky = 0; ky < 5; ++ky) {
            const unsigned int* irow = &sin_[(ty+ky)*36 + tx];
            const unsigned int* wrow = &wt1h[ky*5*12];
            #pragma unroll
            for (int kx = 0; kx < 5; ++kx) {
                unsigned int x = irow[kx];
                const unsigned int* wp = wrow + kx*12;
                #pragma unroll
                for (int c = 0; c < 12; ++c) {
                    unsigned int w = wp[c];
                    CMACH(a[c], x, w);
                }
            }
        }
        #pragma unroll
        for (int c = 0; c < 12; ++c) { PKRELU(hs[c], a[c]); }
    };

    // conv2(+ReLU)+conv3+p-part epilogue for output frame tc
    auto do_out = [&](int tc, unsigned int (&hp)[12], unsigned int (&hc)[12],
                      unsigned int (&hn)[12], bool hasP, bool hasN) {
        size_t idx = (size_t)tc*NPIX + (size_t)(X0+ty)*NXY + (Y0+tx);
        float reval = re[idx];             // issue early, hides under MACs
        unsigned int zz[12];
        #pragma unroll
        for (int c = 0; c < 12; ++c) zz[c] = ub2[c];
        if (hasP) {
            #pragma unroll
            for (int c1 = 0; c1 < 12; ++c1) {
                unsigned int x = hp[c1];
                const unsigned int* wp = &wt2h[(c1*3+0)*12];
                #pragma unroll
                for (int c2 = 0; c2 < 12; ++c2) {
                    unsigned int w = wp[c2];
                    CMACH(zz[c2], x, w);
                }
            }
        }
        {
            #pragma unroll
            for (int c1 = 0; c1 < 12; ++c1) {
                unsigned int x = hc[c1];
                const unsigned int* wp = &wt2h[(c1*3+1)*12];
                #pragma unroll
                for (int c2 = 0; c2 < 12; ++c2) {
                    unsigned int w = wp[c2];
                    CMACH(zz[c2], x, w);
                }
            }
        }
        if (hasN) {
            #pragma unroll
            for (int c1 = 0; c1 < 12; ++c1) {
                unsigned int x = hn[c1];
                const unsigned int* wp = &wt2h[(c1*3+2)*12];
                #pragma unroll
                for (int c2 = 0; c2 < 12; ++c2) {
                    unsigned int w = wp[c2];
                    CMACH(zz[c2], x, w);
                }
            }
        }
        float dR = b3v;
        #pragma unroll
        for (int c = 0; c < 12; ++c) {
            unsigned int zr;
            PKRELU(zr, zz[c]);
            __half2 hz = __builtin_bit_cast(__half2, zr);
            dR += __low2float(hz)*rw3[c] - __high2float(hz)*iw3[c];
        }
        out[idx] = (reval - dR * tsc) * pwv;
    };

    // prologue: stage frame fs
    {
        const float* rp = re + (size_t)fs * NPIX;
        const float* ip = im + (size_t)fs * NPIX;
        float pr0 = rp[a0], pi0 = ip[a0];
        float pr1 = 0.f, pi1 = 0.f;
        if (idx1 < 432) { pr1 = rp[a1]; pi1 = ip[a1]; }
        unsigned int* dst = s_inv[fs & 1];
        unsigned int v0 = packh2f(pr0*m0, pi0*m0);
        dst[tid] = v0;
        unsigned int v1 = 0u;
        if (idx1 < 432) { v1 = packh2f(pr1*m1, pi1*m1); dst[idx1] = v1; }
        int fr = fs - z0;                  // in chunk only when z==0 (fr=0)
        if (fr >= 0 && fr < CH) {
            if (ctr0) s_x5[fr][cadr0] = v0;
            if (idx1 < 432 && ctr1) s_x5[fr][cadr1] = v1;
        }
    }
    __syncthreads();

    #pragma unroll 1
    for (int f = fs; f <= fe; ++f) {
        // (1) issue next frame's loads early -> regs (latency hides under compute)
        float pr0 = 0.f, pi0 = 0.f, pr1 = 0.f, pi1 = 0.f;
        const bool more = (f < fe);
        if (more) {
            const float* rp = re + (size_t)(f+1) * NPIX;
            const float* ip = im + (size_t)(f+1) * NPIX;
            pr0 = rp[a0]; pi0 = ip[a0];
            if (idx1 < 432) { pr1 = rp[a1]; pi1 = ip[a1]; }
        }
        // (2) compute on already-staged frame f
        conv1_to(f, hC);
        const int tc = f - 1;
        if (f > fs && tc >= z0)
            do_out(tc, hA, hB, hC, tc >= 1, true);
        // (3) write prefetched regs to the other LDS buffer, then one barrier
        if (more) {
            unsigned int* dst = s_inv[(f+1) & 1];
            unsigned int v0 = packh2f(pr0*m0, pi0*m0);
            dst[tid] = v0;
            unsigned int v1 = 0u;
            if (idx1 < 432) { v1 = packh2f(pr1*m1, pi1*m1); dst[idx1] = v1; }
            int fr = (f + 1) - z0;
            if (fr >= 0 && fr < CH) {
                if (ctr0) s_x5[fr][cadr0] = v0;
                if (idx1 < 432 && ctr1) s_x5[fr][cadr1] = v1;
            }
        }
        __syncthreads();
        #pragma unroll
        for (int c = 0; c < 12; ++c) { hA[c] = hB[c]; hB[c] = hC[c]; }
    }
    // final frame of the last chunk: tc = 24
    if (fe == NT - 1)
        do_out(NT - 1, hA, hB, hC, true, false);

    // ---- fused k_final: out += Re(Wavg . x5) * (1 - p_w) for the chunk's 5 frames.
    // s_x5 writes are barrier-ordered (every stage is followed by __syncthreads).
    // out[idx] was written by THIS thread above -> per-thread RMW is ordered.
    {
        const int X = X0 + ty, Y = Y0 + tx;
        int i_lo = (X - 4) / SXY; if (i_lo < 0) i_lo = 0;
        int i_hi = X / SXY;       if (i_hi > 3) i_hi = 3;
        int j_lo = (Y - 4) / SXY; if (j_lo < 0) j_lo = 0;
        int j_hi = Y / SXY;       if (j_hi > 3) j_hi = 3;
        const float* wa = gA + (size_t)(z*49 + (i_lo + i_hi)*7 + (j_lo + j_hi)) * 50;
        float xr5[5], xi5[5];
        #pragma unroll
        for (int r = 0; r < 5; ++r) {
            __half2 hx = __builtin_bit_cast(__half2, s_x5[r][ty*TW + tx]);
            xr5[r] = __low2float(hx); xi5[r] = __high2float(hx);
        }
        #pragma unroll
        for (int tl = 0; tl < 5; ++tl) {
            float qr = 0.f;
            #pragma unroll
            for (int r = 0; r < 5; ++r)
                qr += wa[(tl*5+r)*2] * xr5[r] - wa[(tl*5+r)*2+1] * xi5[r];
            size_t oidx = (size_t)(z0 + tl)*NPIX + (size_t)X*NXY + Y;
            out[oidx] += qr * qwv;
        }
    }
}

extern "C" void kernel_launch(void* const* d_in, const int* in_sizes, int n_in,
                              void* d_out, int out_size, void* d_ws, size_t ws_size,
                              hipStream_t stream)
{
    const float* re    = (const float*)d_in[0];
    const float* im    = (const float*)d_in[1];
    const float* w1r   = (const float*)d_in[2];
    const float* w1i   = (const float*)d_in[3];
    const float* b1r   = (const float*)d_in[4];
    const float* b1i   = (const float*)d_in[5];
    const float* w2r   = (const float*)d_in[6];
    const float* w2i   = (const float*)d_in[7];
    const float* b2r   = (const float*)d_in[8];
    const float* b2i   = (const float*)d_in[9];
    const float* w3r   = (const float*)d_in[10];
    const float* w3i   = (const float*)d_in[11];
    const float* b3r   = (const float*)d_in[12];
    const float* thres = (const float*)d_in[14];
    const float* tau_w = (const float*)d_in[15];
    const float* p_w   = (const float*)d_in[16];
    const int* num_iter= (const int*)d_in[17];

    float* ws = (float*)d_ws;
    unsigned int* wt1h = (unsigned int*)ws;          // 300 uints (padded 512)
    unsigned int* wt2h = wt1h + 512;                 // 432 uints (padded 512)
    unsigned int* wbh  = wt2h + 512;                 // 24 uints (padded 64)
    float* gP  = (float*)(wbh + 64);                 // 80*GSL*50 = 32000 floats
    float* gA  = gP + 80*GSL*50;                     // 245*50 floats

    float* outf = (float*)d_out;

    // K1: gram partials (640 blocks) + weight packing (8 blocks) — inputs only
    k_pre<<<648, 256, 0, stream>>>(re, im, w1r, w1i, w2r, w2i,
                                   b1r, b1i, b2r, b2i,
                                   wt1h, wt2h, wbh, gP);
    // K2: eig + region-average -> gA
    k_post<<<1, 128, 0, stream>>>(gP, thres, gA);
    // K3: conv pipeline with fused final epilogue (k_final eliminated)
    dim3 g1(NXY/TW, NXY/TH, NZ);
    k_work<<<g1, 256, 0, stream>>>(re, im, wt1h, wt2h, wbh,
                                   w3r, w3i, b3r,
                                   tau_w, p_w, num_iter, gA, outf);
}

// Round 10
// 399.448 us; speedup vs baseline: 1.1603x; 1.1603x over previous
//
#include <hip/hip_runtime.h>
#include <hip/hip_fp16.h>

#define NT 25
#define NXY 448
#define NPIX (448*448)
#define PXY 115
#define SXY 111

#define TW 32
#define TH 8
#define CH 5          // output frames per time-chunk
#define NZ 5          // number of time chunks (NT/CH)
#define GSL 8         // gram spatial slices

typedef float f32x4 __attribute__((ext_vector_type(4)));
typedef unsigned int uint2v __attribute__((ext_vector_type(2)));
typedef unsigned int uint4v __attribute__((ext_vector_type(4)));

// complex MAC, packed fp16 (conv1 path, unchanged)
#define CMACH(z, x, w)                                                                             \
    asm("v_pk_fma_f16 %0, %1, %2, %0 op_sel:[0,0,0] op_sel_hi:[0,1,1]"                             \
        : "+v"(z) : "v"(x), "s"(w));                                                               \
    asm("v_pk_fma_f16 %0, %1, %2, %0 op_sel:[1,1,0] op_sel_hi:[1,0,1] neg_lo:[0,1,0]"              \
        : "+v"(z) : "v"(x), "s"(w));

#define PKRELU(d, a)                                                                               \
    asm("v_pk_max_f16 %0, %1, 0" : "=v"(d) : "v"(a))

// MFMA 16x16x16 f16: D = A(16x16) * B(16x16) + D, fp32 accum.
// A: lane l holds A[l%16][4*(l/16)+j]; B: lane l holds B[4*(l/16)+j][l%16];
// D: lane l holds D[4*(l/16)+j][l%16]  (m89-verified 16x16 C/D map).
#define MFMA16(acc, a, b)                                                                          \
    asm("v_mfma_f32_16x16x16_f16 %0, %1, %2, %0" : "+v"(acc) : "v"(a), "v"(b))

static __device__ __forceinline__ unsigned int packh2f(float lo, float hi) {
    auto h = __builtin_amdgcn_cvt_pkrtz(lo, hi);
    return __builtin_bit_cast(unsigned int, h);
}

// ---------------- K1: gram partials (gid<640) + weight packing (gid>=640)
// wt1h: conv1 weights (tap-major, fp16 (re,im) words) for the VALU conv1 path.
// wbh[0..11]: packed b1.
// wt2m: conv2 weights pre-packed in MFMA B-fragment order:
//   frag (dt, hf, u): lane l, elem j: B[k][n], k = 16*hf + 4*(l/16) + j (real-K,
//   interleaved re/im per input ch: k=2c re, 2c+1 im), n = 16*u + l%16
//   (outputs [re0..11, im0..11]). Rows k>=24 and cols n>=24 are ZERO (safe pad).
__global__ __launch_bounds__(256) void k_pre(
    const float* __restrict__ re, const float* __restrict__ im,
    const float* __restrict__ w1r, const float* __restrict__ w1i,
    const float* __restrict__ w2r, const float* __restrict__ w2i,
    const float* __restrict__ b1r, const float* __restrict__ b1i,
    unsigned int* __restrict__ wt1h, unsigned int* __restrict__ wbh,
    unsigned int* __restrict__ wt2m, float* __restrict__ gP)
{
    const int gid = blockIdx.x;
    const int tid = threadIdx.x;

    if (gid >= 640) {
        int i = (gid - 640) * 256 + tid;
        auto pkf = [](float a, float b) {
            unsigned short ua = __half_as_ushort(__float2half_rn(a));
            unsigned short ub = __half_as_ushort(__float2half_rn(b));
            return (unsigned int)ua | ((unsigned int)ub << 16);
        };
        if (i < 300) {
            int c = i / 25, tap = i - c * 25;
            wt1h[tap*12 + c] = pkf(w1r[i], w1i[i]);
        }
        if (i < 12) wbh[i] = pkf(b1r[i], b1i[i]);
        if (i < 768) {
            int l = i & 63; int t = i >> 6;
            int u = t & 1, hf = (t >> 1) & 1, d = t >> 2;
            unsigned short us[4];
            #pragma unroll
            for (int j = 0; j < 4; ++j) {
                int k = 16*hf + 4*(l >> 4) + j;
                int n = 16*u + (l & 15);
                float v = 0.f;
                if (k < 24 && n < 24) {
                    int cin = k >> 1; bool imin = (k & 1) != 0;
                    int cout = (n < 12) ? n : n - 12; bool reout = n < 12;
                    float wre = w2r[(cout*12 + cin)*3 + d];
                    float wim = w2i[(cout*12 + cin)*3 + d];
                    v = !imin ? (reout ? wre : wim) : (reout ? -wim : wre);
                }
                us[j] = __half_as_ushort(__float2half_rn(v));
            }
            wt2m[i*2]   = (unsigned int)us[0] | ((unsigned int)us[1] << 16);
            wt2m[i*2+1] = (unsigned int)us[2] | ((unsigned int)us[3] << 16);
        }
        return;
    }

    // ---- gram path (unchanged) ----
    __shared__ float s_red[4][50];
    const int b = gid >> 3;
    const int slice = gid & 7;
    const int chunk = b >> 4;
    const int pidx = b & 15;
    const int X0 = (pidx >> 2) * SXY;
    const int Y0 = (pidx & 3) * SXY;

    float acc[50];
    #pragma unroll
    for (int k = 0; k < 50; ++k) acc[k] = 0.f;

    const int npx = PXY * PXY;
    for (int pi = slice*256 + tid; pi < npx; pi += 256*GSL) {
        int px = pi / PXY, py = pi % PXY;
        size_t base = (size_t)(X0 + px) * NXY + (Y0 + py);
        float xr[5], xi[5];
        #pragma unroll
        for (int r = 0; r < 5; ++r) {
            size_t a = (size_t)(chunk*5 + r) * NPIX + base;
            xr[r] = re[a]; xi[r] = im[a];
        }
        #pragma unroll
        for (int t1 = 0; t1 < 5; ++t1)
            #pragma unroll
            for (int t2 = 0; t2 < 5; ++t2) {
                acc[(t1*5+t2)*2]   += xr[t1]*xr[t2] + xi[t1]*xi[t2];
                acc[(t1*5+t2)*2+1] += xi[t1]*xr[t2] - xr[t1]*xi[t2];
            }
    }
    #pragma unroll
    for (int k = 0; k < 50; ++k) {
        float v = acc[k];
        for (int m = 32; m > 0; m >>= 1) v += __shfl_xor(v, m, 64);
        acc[k] = v;
    }
    int lane = tid & 63, wid = tid >> 6;
    if (lane == 0) {
        #pragma unroll
        for (int k = 0; k < 50; ++k) s_red[wid][k] = acc[k];
    }
    __syncthreads();
    if (tid < 50) {
        gP[(b*GSL + slice)*50 + tid] =
            s_red[0][tid] + s_red[1][tid] + s_red[2][tid] + s_red[3][tid];
    }
}

// ---------------- K2: fold Gram partials -> Jacobi eig -> W (LDS) -> region-avg gA
__global__ __launch_bounds__(128) void k_post(
    const float* __restrict__ gP, const float* __restrict__ thres,
    float* __restrict__ gA)
{
    __shared__ float sW[80*50];
    const int tid = threadIdx.x;
    if (tid < 80) {
        const int b = tid;
        float Ar[5][5], Ai[5][5], Vr[5][5], Vi[5][5];
        #pragma unroll
        for (int a = 0; a < 5; ++a)
            #pragma unroll
            for (int c = 0; c < 5; ++c) {
                float sr = 0.f, si = 0.f;
                #pragma unroll
                for (int sl = 0; sl < GSL; ++sl) {
                    sr += gP[(b*GSL + sl)*50 + (a*5+c)*2];
                    si += gP[(b*GSL + sl)*50 + (a*5+c)*2 + 1];
                }
                Ar[a][c] = sr; Ai[a][c] = si;
                Vr[a][c] = (a==c) ? 1.f : 0.f;
                Vi[a][c] = 0.f;
            }
        for (int sw = 0; sw < 9; ++sw) {
            #pragma unroll
            for (int p = 0; p < 4; ++p) {
                #pragma unroll
                for (int q = p+1; q < 5; ++q) {
                    float apr = Ar[p][q], api = Ai[p][q];
                    float n2 = apr*apr + api*api;
                    if (n2 > 1e-24f) {
                        float mlen = sqrtf(n2);
                        float phr = apr / mlen, phi = api / mlen;
                        float tau = (Ar[q][q] - Ar[p][p]) / (2.f * mlen);
                        float tt = (tau >= 0.f ? 1.f : -1.f) / (fabsf(tau) + sqrtf(1.f + tau*tau));
                        float cc = 1.f / sqrtf(1.f + tt*tt);
                        float ss = tt * cc;
                        float wr2 = ss * phr, wi2 = ss * phi;
                        #pragma unroll
                        for (int k = 0; k < 5; ++k) {
                            float xr = Ar[k][p], xi2 = Ai[k][p];
                            float yr = Ar[k][q], yi = Ai[k][q];
                            Ar[k][p] = cc*xr - (wr2*yr + wi2*yi);
                            Ai[k][p] = cc*xi2 - (wr2*yi - wi2*yr);
                            Ar[k][q] = wr2*xr - wi2*xi2 + cc*yr;
                            Ai[k][q] = wr2*xi2 + wi2*xr + cc*yi;
                            float vxr = Vr[k][p], vxi = Vi[k][p];
                            float vyr = Vr[k][q], vyi = Vi[k][q];
                            Vr[k][p] = cc*vxr - (wr2*vyr + wi2*vyi);
                            Vi[k][p] = cc*vxi - (wr2*vyi - wi2*vyr);
                            Vr[k][q] = wr2*vxr - wi2*vxi + cc*vyr;
                            Vi[k][q] = wr2*vxi + wi2*vxr + cc*vyi;
                        }
                        #pragma unroll
                        for (int k = 0; k < 5; ++k) {
                            float xr = Ar[p][k], xi2 = Ai[p][k];
                            float yr = Ar[q][k], yi = Ai[q][k];
                            Ar[p][k] = cc*xr - (wr2*yr - wi2*yi);
                            Ai[p][k] = cc*xi2 - (wr2*yi + wi2*yr);
                            Ar[q][k] = wr2*xr + wi2*xi2 + cc*yr;
                            Ai[q][k] = wr2*xi2 - wi2*xr + cc*yi;
                        }
                    }
                }
            }
        }
        float sv[5], s0 = 0.f;
        #pragma unroll
        for (int k = 0; k < 5; ++k) { sv[k] = sqrtf(fmaxf(Ar[k][k], 0.f)); s0 = fmaxf(s0, sv[k]); }
        float th = fmaxf(thres[b], 0.f) * s0;
        float ratio[5];
        #pragma unroll
        for (int k = 0; k < 5; ++k)
            ratio[k] = sv[k] > 0.f ? fmaxf(sv[k] - th, 0.f) / sv[k] : 0.f;
        #pragma unroll
        for (int a = 0; a < 5; ++a)
            #pragma unroll
            for (int c = 0; c < 5; ++c) {
                float wr = 0.f, wi = 0.f;
                #pragma unroll
                for (int k = 0; k < 5; ++k) {
                    wr += ratio[k] * (Vr[a][k]*Vr[c][k] + Vi[a][k]*Vi[c][k]);
                    wi += ratio[k] * (Vi[a][k]*Vr[c][k] - Vr[a][k]*Vi[c][k]);
                }
                sW[b*50 + (a*5+c)*2]   = wr;
                sW[b*50 + (a*5+c)*2+1] = wi;
            }
    }
    __syncthreads();
    for (int it = tid; it < 245*25; it += 128) {
        int blk = it / 25, e = it % 25;
        int chunk = blk / 49;
        int rem = blk % 49;
        int rx = rem / 7, ry = rem % 7;
        int i0 = rx >> 1, i1 = (rx + 1) >> 1;
        int j0 = ry >> 1, j1 = (ry + 1) >> 1;
        float sr = 0.f, si = 0.f; int cnt = 0;
        for (int i = i0; i <= i1; ++i)
            for (int j = j0; j <= j1; ++j) {
                int b = chunk*16 + i*4 + j;
                sr += sW[b*50 + e*2];
                si += sW[b*50 + e*2 + 1];
                ++cnt;
            }
        float inv = 1.f / (float)cnt;
        gA[blk*50 + e*2]   = sr * inv;
        gA[blk*50 + e*2+1] = si * inv;
    }
}

// ---------------- K3: conv pipeline. conv1 = VALU pk_fma_f16 (unchanged);
// conv2+conv3 = MFMA 16x16x16_f16 on the idle matrix pipe, fp32 accumulate.
// h ring: per-wave LDS [3 slots][64 px][24 f16] ((re,im)-interleaved channels —
// exactly conv1's packed output order, written as 3x ds_write_b128).
// p-part goes to s_pout (LDS); final per-thread epilogue adds q-part (x5/gA)
// and writes out[] exactly once (no global RMW).
__global__ __launch_bounds__(256, 4) void k_work(
    const float* __restrict__ re, const float* __restrict__ im,
    const unsigned int* __restrict__ wt1h, const uint2v* __restrict__ wt2m,
    const unsigned int* __restrict__ wbh,
    const float* __restrict__ w3r, const float* __restrict__ w3i,
    const float* __restrict__ b3r,
    const float* __restrict__ b2re, const float* __restrict__ b2im,
    const float* __restrict__ tau_w, const float* __restrict__ p_w,
    const int* __restrict__ num_iter,
    const float* __restrict__ gA,
    float* __restrict__ out)
{
    __shared__ unsigned int s_inv[2][12*36];                 // fp16 (re,im) input tile
    __shared__ __attribute__((aligned(16))) _Float16 h_lds[4][3][64*24 + 16];
    __shared__ unsigned int s_x5[CH][TH*TW];                 // own-pixel fp16 (re,im)
    __shared__ float s_pout[CH][TH*TW];                      // p-part per pixel

    const int tid = threadIdx.x;
    const int tx = tid & 31;
    const int ty = tid >> 5;
    const int wv = tid >> 6;          // wave id (0..3)
    const int lane = tid & 63;
    const int nn = lane & 15;         // MFMA n / row-group index
    const int hq = lane >> 4;         // MFMA k-quad / row-block index
    const int Y0 = blockIdx.x * TW;
    const int X0 = blockIdx.y * TH;
    const int z  = blockIdx.z;
    const int z0 = z * CH;
    const int fs = (z == 0) ? 0 : z0 - 1;
    const int fe = (z0 + CH < NT) ? z0 + CH : NT - 1;

    // conv1 bias (SGPR path)
    unsigned int ub1[12];
    #pragma unroll
    for (int c = 0; c < 12; ++c) ub1[c] = wbh[c];

    const float b3v = b3r[0];
    const float pw_raw = p_w[0];
    const float tsc = fmaxf(tau_w[0], 0.f) / (float)num_iter[0];
    const float pwv = fmaxf(pw_raw, 0.f);
    const float qwv = 1.f - pw_raw;

    // per-lane conv3 factors and conv2 bias by D-column
    const float fac0 = (nn < 12) ? w3r[nn] : -w3i[nn - 12];
    const float fac1 = (nn < 8)  ? -w3i[nn + 4] : 0.f;
    const float bi0  = (nn < 12) ? b2re[nn] : b2im[nn - 12];
    const float bi1  = (nn < 8)  ? b2im[nn + 4] : 0.f;

    // conv2 B-fragments: persistent VGPRs (loaded once, L2-hot)
    uint2v B2f[3][2][2];
    #pragma unroll
    for (int d = 0; d < 3; ++d)
        #pragma unroll
        for (int hf = 0; hf < 2; ++hf)
            #pragma unroll
            for (int u = 0; u < 2; ++u)
                B2f[d][hf][u] = wt2m[((d*2 + hf)*2 + u)*64 + lane];

    // staging geometry
    const int idx1 = tid + 256;
    int r0 = tid / 36, c0 = tid - r0*36;
    int gx0 = X0 + r0 - 2, gy0 = Y0 + c0 - 2;
    bool k0 = (gx0 >= 0) && (gx0 < NXY) && (gy0 >= 0) && (gy0 < NXY);
    const int a0 = (k0 ? gx0 : 0) * NXY + (k0 ? gy0 : 0);
    const float m0 = k0 ? 1.f : 0.f;
    const bool ctr0 = (r0 >= 2) && (c0 >= 2) && (c0 < 34);
    const int cadr0 = (r0-2)*TW + (c0-2);
    int r1 = idx1 / 36, c1_ = idx1 - r1*36;
    int gx1 = X0 + r1 - 2, gy1 = Y0 + c1_ - 2;
    bool k1 = (gx1 >= 0) && (gx1 < NXY) && (gy1 >= 0) && (gy1 < NXY);
    const int a1 = (k1 ? gx1 : 0) * NXY + (k1 ? gy1 : 0);
    const float m1 = k1 ? 1.f : 0.f;
    const bool ctr1 = (r1 < 10) && (c1_ >= 2) && (c1_ < 34);
    const int cadr1 = (r1-2)*TW + (c1_-2);

    // conv1 for frame tf -> relu -> h ring slot tf%3
    auto conv1_to = [&](int tf) {
        unsigned int a[12];
        #pragma unroll
        for (int c = 0; c < 12; ++c) a[c] = ub1[c];
        const unsigned int* sin_ = s_inv[tf & 1];
        #pragma unroll 1
        for (int ky = 0; ky < 5; ++ky) {
            const unsigned int* irow = &sin_[(ty+ky)*36 + tx];
            const unsigned int* wrow = &wt1h[ky*5*12];
            #pragma unroll
            for (int kx = 0; kx < 5; ++kx) {
                unsigned int x = irow[kx];
                const unsigned int* wp = wrow + kx*12;
                #pragma unroll
                for (int c = 0; c < 12; ++c) {
                    unsigned int w = wp[c];
                    CMACH(a[c], x, w);
                }
            }
        }
        unsigned int hs[12];
        #pragma unroll
        for (int c = 0; c < 12; ++c) { PKRELU(hs[c], a[c]); }
        _Float16* hb = &h_lds[wv][tf % 3][lane * 24];
        ((uint4v*)hb)[0] = uint4v{hs[0], hs[1], hs[2],  hs[3]};
        ((uint4v*)hb)[1] = uint4v{hs[4], hs[5], hs[6],  hs[7]};
        ((uint4v*)hb)[2] = uint4v{hs[8], hs[9], hs[10], hs[11]};
    };

    // conv2 (MFMA) + conv3 (reduce) + p-part for output frame tc
    auto do_out = [&](int tc, bool hasP, bool hasN) {
        const int sP = (tc + 2) % 3, sC = tc % 3, sN = (tc + 1) % 3;
        f32x4 acc[4][2];
        #pragma unroll
        for (int m = 0; m < 4; ++m) {
            acc[m][0] = f32x4{bi0, bi0, bi0, bi0};
            acc[m][1] = f32x4{bi1, bi1, bi1, bi1};
        }
        #pragma unroll
        for (int m = 0; m < 4; ++m) {
            #pragma unroll
            for (int d = 0; d < 3; ++d) {
                if (d == 0 && !hasP) continue;
                if (d == 2 && !hasN) continue;
                const int slot = (d == 0) ? sP : ((d == 1) ? sC : sN);
                #pragma unroll
                for (int hf = 0; hf < 2; ++hf) {
                    uint2v af = *(const uint2v*)
                        &h_lds[wv][slot][(16*m + nn)*24 + 16*hf + 4*hq];
                    MFMA16(acc[m][0], af, B2f[d][hf][0]);
                    MFMA16(acc[m][1], af, B2f[d][hf][1]);
                }
            }
        }
        const int fr = tc - z0;
        #pragma unroll
        for (int m = 0; m < 4; ++m) {
            float v0_ = fmaxf(acc[m][0][0], 0.f)*fac0 + fmaxf(acc[m][1][0], 0.f)*fac1;
            float v1_ = fmaxf(acc[m][0][1], 0.f)*fac0 + fmaxf(acc[m][1][1], 0.f)*fac1;
            float v2_ = fmaxf(acc[m][0][2], 0.f)*fac0 + fmaxf(acc[m][1][2], 0.f)*fac1;
            float v3_ = fmaxf(acc[m][0][3], 0.f)*fac0 + fmaxf(acc[m][1][3], 0.f)*fac1;
            #pragma unroll
            for (int mask = 1; mask <= 8; mask <<= 1) {
                v0_ += __shfl_xor(v0_, mask, 64);
                v1_ += __shfl_xor(v1_, mask, 64);
                v2_ += __shfl_xor(v2_, mask, 64);
                v3_ += __shfl_xor(v3_, mask, 64);
            }
            // writers: lane nn==r publishes pixel 16m+4hq+r
            #pragma unroll
            for (int r = 0; r < 4; ++r) {
                float vr = (r == 0) ? v0_ : (r == 1) ? v1_ : (r == 2) ? v2_ : v3_;
                if (nn == r) {
                    int pl = wv*64 + 16*m + 4*hq + r;
                    __half2 hx = __builtin_bit_cast(__half2, s_x5[fr][pl]);
                    float reval = __low2float(hx);
                    s_pout[fr][pl] = (reval - (vr + b3v)*tsc) * pwv;
                }
            }
        }
    };

    // prologue: stage frame fs
    {
        const float* rp = re + (size_t)fs * NPIX;
        const float* ip = im + (size_t)fs * NPIX;
        float pr0 = rp[a0], pi0 = ip[a0];
        float pr1 = 0.f, pi1 = 0.f;
        if (idx1 < 432) { pr1 = rp[a1]; pi1 = ip[a1]; }
        unsigned int* dst = s_inv[fs & 1];
        unsigned int v0 = packh2f(pr0*m0, pi0*m0);
        dst[tid] = v0;
        unsigned int v1 = 0u;
        if (idx1 < 432) { v1 = packh2f(pr1*m1, pi1*m1); dst[idx1] = v1; }
        int fr = fs - z0;
        if (fr >= 0 && fr < CH) {
            if (ctr0) s_x5[fr][cadr0] = v0;
            if (idx1 < 432 && ctr1) s_x5[fr][cadr1] = v1;
        }
    }
    __syncthreads();

    #pragma unroll 1
    for (int f = fs; f <= fe; ++f) {
        float pr0 = 0.f, pi0 = 0.f, pr1 = 0.f, pi1 = 0.f;
        const bool more = (f < fe);
        if (more) {
            const float* rp = re + (size_t)(f+1) * NPIX;
            const float* ip = im + (size_t)(f+1) * NPIX;
            pr0 = rp[a0]; pi0 = ip[a0];
            if (idx1 < 432) { pr1 = rp[a1]; pi1 = ip[a1]; }
        }
        conv1_to(f);
        const int tc = f - 1;
        if (f > fs && tc >= z0)
            do_out(tc, tc >= 1, true);
        if (more) {
            unsigned int* dst = s_inv[(f+1) & 1];
            unsigned int v0 = packh2f(pr0*m0, pi0*m0);
            dst[tid] = v0;
            unsigned int v1 = 0u;
            if (idx1 < 432) { v1 = packh2f(pr1*m1, pi1*m1); dst[idx1] = v1; }
            int fr = (f + 1) - z0;
            if (fr >= 0 && fr < CH) {
                if (ctr0) s_x5[fr][cadr0] = v0;
                if (idx1 < 432 && ctr1) s_x5[fr][cadr1] = v1;
            }
        }
        __syncthreads();
    }
    if (fe == NT - 1)
        do_out(NT - 1, true, false);

    // ---- final epilogue: out = p-part + Re(Wavg . x5)*(1-p_w), one store per px
    __syncthreads();
    {
        const int X = X0 + ty, Y = Y0 + tx;
        int i_lo = (X - 4) / SXY; if (i_lo < 0) i_lo = 0;
        int i_hi = X / SXY;       if (i_hi > 3) i_hi = 3;
        int j_lo = (Y - 4) / SXY; if (j_lo < 0) j_lo = 0;
        int j_hi = Y / SXY;       if (j_hi > 3) j_hi = 3;
        const float* wa = gA + (size_t)(z*49 + (i_lo + i_hi)*7 + (j_lo + j_hi)) * 50;
        float xr5[5], xi5[5];
        #pragma unroll
        for (int r = 0; r < 5; ++r) {
            __half2 hx = __builtin_bit_cast(__half2, s_x5[r][tid]);
            xr5[r] = __low2float(hx); xi5[r] = __high2float(hx);
        }
        #pragma unroll
        for (int tl = 0; tl < 5; ++tl) {
            float qr = 0.f;
            #pragma unroll
            for (int r = 0; r < 5; ++r)
                qr += wa[(tl*5+r)*2] * xr5[r] - wa[(tl*5+r)*2+1] * xi5[r];
            out[(size_t)(z0 + tl)*NPIX + (size_t)X*NXY + Y] = s_pout[tl][tid] + qr * qwv;
        }
    }
}

extern "C" void kernel_launch(void* const* d_in, const int* in_sizes, int n_in,
                              void* d_out, int out_size, void* d_ws, size_t ws_size,
                              hipStream_t stream)
{
    const float* re    = (const float*)d_in[0];
    const float* im    = (const float*)d_in[1];
    const float* w1r   = (const float*)d_in[2];
    const float* w1i   = (const float*)d_in[3];
    const float* b1r   = (const float*)d_in[4];
    const float* b1i   = (const float*)d_in[5];
    const float* w2r   = (const float*)d_in[6];
    const float* w2i   = (const float*)d_in[7];
    const float* b2r   = (const float*)d_in[8];
    const float* b2i   = (const float*)d_in[9];
    const float* w3r   = (const float*)d_in[10];
    const float* w3i   = (const float*)d_in[11];
    const float* b3r   = (const float*)d_in[12];
    const float* thres = (const float*)d_in[14];
    const float* tau_w = (const float*)d_in[15];
    const float* p_w   = (const float*)d_in[16];
    const int* num_iter= (const int*)d_in[17];

    float* ws = (float*)d_ws;
    unsigned int* wt1h = (unsigned int*)ws;          // 300 uints (pad 512)
    unsigned int* wbh  = wt1h + 512;                 // 12 uints (pad 64)
    unsigned int* wt2m = wbh + 64;                   // 768 uint2 = 1536 uints
    float* gP  = (float*)(wt2m + 1536);              // 80*GSL*50 floats
    float* gA  = gP + 80*GSL*50;                     // 245*50 floats

    float* outf = (float*)d_out;

    k_pre<<<648, 256, 0, stream>>>(re, im, w1r, w1i, w2r, w2i, b1r, b1i,
                                   wt1h, wbh, wt2m, gP);
    k_post<<<1, 128, 0, stream>>>(gP, thres, gA);
    dim3 g1(NXY/TW, NXY/TH, NZ);
    k_work<<<g1, 256, 0, stream>>>(re, im, wt1h, (const uint2v*)wt2m, wbh,
                                   w3r, w3i, b3r, b2r, b2i,
                                   tau_w, p_w, num_iter, gA, outf);
}

// Round 12
// 399.411 us; speedup vs baseline: 1.1604x; 1.0001x over previous
//
#include <hip/hip_runtime.h>
#include <hip/hip_fp16.h>

#define NT 25
#define NXY 448
#define NPIX (448*448)
#define PXY 115
#define SXY 111

#define TW 32
#define TH 8
#define CH 5          // output frames per time-chunk
#define NZ 5          // number of time chunks (NT/CH)
#define GSL 8         // gram spatial slices

typedef float f32x4 __attribute__((ext_vector_type(4)));
typedef unsigned int uint2v __attribute__((ext_vector_type(2)));
typedef unsigned int uint4v __attribute__((ext_vector_type(4)));

// complex MAC, packed fp16 (conv1 path)
#define CMACH(z, x, w)                                                                             \
    asm("v_pk_fma_f16 %0, %1, %2, %0 op_sel:[0,0,0] op_sel_hi:[0,1,1]"                             \
        : "+v"(z) : "v"(x), "s"(w));                                                               \
    asm("v_pk_fma_f16 %0, %1, %2, %0 op_sel:[1,1,0] op_sel_hi:[1,0,1] neg_lo:[0,1,0]"              \
        : "+v"(z) : "v"(x), "s"(w));

#define PKRELU(d, a)                                                                               \
    asm("v_pk_max_f16 %0, %1, 0" : "=v"(d) : "v"(a))

// MFMA 16x16x16 f16: D = A(16x16) * B(16x16) + D, fp32 accum.
// A: lane l holds A[l%16][4*(l/16)+j]; B: lane l holds B[4*(l/16)+j][l%16];
// D: lane l holds D[4*(l/16)+j][l%16]  (HW-verified by r10's conv2 pass).
#define MFMA16(acc, a, b)                                                                          \
    asm("v_mfma_f32_16x16x16_f16 %0, %1, %2, %0" : "+v"(acc) : "v"(a), "v"(b))

static __device__ __forceinline__ unsigned int packh2f(float lo, float hi) {
    auto h = __builtin_amdgcn_cvt_pkrtz(lo, hi);
    return __builtin_bit_cast(unsigned int, h);
}

// ---------------- K1: gram partials (gid<640) + weight packing (gid>=640)
__global__ __launch_bounds__(256) void k_pre(
    const float* __restrict__ re, const float* __restrict__ im,
    const float* __restrict__ w1r, const float* __restrict__ w1i,
    const float* __restrict__ w2r, const float* __restrict__ w2i,
    const float* __restrict__ b1r, const float* __restrict__ b1i,
    unsigned int* __restrict__ wt1h, unsigned int* __restrict__ wbh,
    unsigned int* __restrict__ wt2m, float* __restrict__ gP)
{
    const int gid = blockIdx.x;
    const int tid = threadIdx.x;

    if (gid >= 640) {
        int i = (gid - 640) * 256 + tid;
        auto pkf = [](float a, float b) {
            unsigned short ua = __half_as_ushort(__float2half_rn(a));
            unsigned short ub = __half_as_ushort(__float2half_rn(b));
            return (unsigned int)ua | ((unsigned int)ub << 16);
        };
        if (i < 300) {
            int c = i / 25, tap = i - c * 25;
            wt1h[tap*12 + c] = pkf(w1r[i], w1i[i]);
        }
        if (i < 12) wbh[i] = pkf(b1r[i], b1i[i]);
        if (i < 768) {
            int l = i & 63; int t = i >> 6;
            int u = t & 1, hf = (t >> 1) & 1, d = t >> 2;
            unsigned short us[4];
            #pragma unroll
            for (int j = 0; j < 4; ++j) {
                int k = 16*hf + 4*(l >> 4) + j;
                int n = 16*u + (l & 15);
                float v = 0.f;
                if (k < 24 && n < 24) {
                    int cin = k >> 1; bool imin = (k & 1) != 0;
                    int cout = (n < 12) ? n : n - 12; bool reout = n < 12;
                    float wre = w2r[(cout*12 + cin)*3 + d];
                    float wim = w2i[(cout*12 + cin)*3 + d];
                    v = !imin ? (reout ? wre : wim) : (reout ? -wim : wre);
                }
                us[j] = __half_as_ushort(__float2half_rn(v));
            }
            wt2m[i*2]   = (unsigned int)us[0] | ((unsigned int)us[1] << 16);
            wt2m[i*2+1] = (unsigned int)us[2] | ((unsigned int)us[3] << 16);
        }
        return;
    }

    // ---- gram path ----
    __shared__ float s_red[4][50];
    const int b = gid >> 3;
    const int slice = gid & 7;
    const int chunk = b >> 4;
    const int pidx = b & 15;
    const int X0 = (pidx >> 2) * SXY;
    const int Y0 = (pidx & 3) * SXY;

    float acc[50];
    #pragma unroll
    for (int k = 0; k < 50; ++k) acc[k] = 0.f;

    const int npx = PXY * PXY;
    for (int pi = slice*256 + tid; pi < npx; pi += 256*GSL) {
        int px = pi / PXY, py = pi % PXY;
        size_t base = (size_t)(X0 + px) * NXY + (Y0 + py);
        float xr[5], xi[5];
        #pragma unroll
        for (int r = 0; r < 5; ++r) {
            size_t a = (size_t)(chunk*5 + r) * NPIX + base;
            xr[r] = re[a]; xi[r] = im[a];
        }
        #pragma unroll
        for (int t1 = 0; t1 < 5; ++t1)
            #pragma unroll
            for (int t2 = 0; t2 < 5; ++t2) {
                acc[(t1*5+t2)*2]   += xr[t1]*xr[t2] + xi[t1]*xi[t2];
                acc[(t1*5+t2)*2+1] += xi[t1]*xr[t2] - xr[t1]*xi[t2];
            }
    }
    #pragma unroll
    for (int k = 0; k < 50; ++k) {
        float v = acc[k];
        for (int m = 32; m > 0; m >>= 1) v += __shfl_xor(v, m, 64);
        acc[k] = v;
    }
    int lane = tid & 63, wid = tid >> 6;
    if (lane == 0) {
        #pragma unroll
        for (int k = 0; k < 50; ++k) s_red[wid][k] = acc[k];
    }
    __syncthreads();
    if (tid < 50) {
        gP[(b*GSL + slice)*50 + tid] =
            s_red[0][tid] + s_red[1][tid] + s_red[2][tid] + s_red[3][tid];
    }
}

// ---------------- K2: fold Gram partials -> Jacobi eig -> W (LDS) -> region-avg gA
__global__ __launch_bounds__(128) void k_post(
    const float* __restrict__ gP, const float* __restrict__ thres,
    float* __restrict__ gA)
{
    __shared__ float sW[80*50];
    const int tid = threadIdx.x;
    if (tid < 80) {
        const int b = tid;
        float Ar[5][5], Ai[5][5], Vr[5][5], Vi[5][5];
        #pragma unroll
        for (int a = 0; a < 5; ++a)
            #pragma unroll
            for (int c = 0; c < 5; ++c) {
                float sr = 0.f, si = 0.f;
                #pragma unroll
                for (int sl = 0; sl < GSL; ++sl) {
                    sr += gP[(b*GSL + sl)*50 + (a*5+c)*2];
                    si += gP[(b*GSL + sl)*50 + (a*5+c)*2 + 1];
                }
                Ar[a][c] = sr; Ai[a][c] = si;
                Vr[a][c] = (a==c) ? 1.f : 0.f;
                Vi[a][c] = 0.f;
            }
        for (int sw = 0; sw < 9; ++sw) {
            #pragma unroll
            for (int p = 0; p < 4; ++p) {
                #pragma unroll
                for (int q = p+1; q < 5; ++q) {
                    float apr = Ar[p][q], api = Ai[p][q];
                    float n2 = apr*apr + api*api;
                    if (n2 > 1e-24f) {
                        float mlen = sqrtf(n2);
                        float phr = apr / mlen, phi = api / mlen;
                        float tau = (Ar[q][q] - Ar[p][p]) / (2.f * mlen);
                        float tt = (tau >= 0.f ? 1.f : -1.f) / (fabsf(tau) + sqrtf(1.f + tau*tau));
                        float cc = 1.f / sqrtf(1.f + tt*tt);
                        float ss = tt * cc;
                        float wr2 = ss * phr, wi2 = ss * phi;
                        #pragma unroll
                        for (int k = 0; k < 5; ++k) {
                            float xr = Ar[k][p], xi2 = Ai[k][p];
                            float yr = Ar[k][q], yi = Ai[k][q];
                            Ar[k][p] = cc*xr - (wr2*yr + wi2*yi);
                            Ai[k][p] = cc*xi2 - (wr2*yi - wi2*yr);
                            Ar[k][q] = wr2*xr - wi2*xi2 + cc*yr;
                            Ai[k][q] = wr2*xi2 + wi2*xr + cc*yi;
                            float vxr = Vr[k][p], vxi = Vi[k][p];
                            float vyr = Vr[k][q], vyi = Vi[k][q];
                            Vr[k][p] = cc*vxr - (wr2*vyr + wi2*vyi);
                            Vi[k][p] = cc*vxi - (wr2*vyi - wi2*vyr);
                            Vr[k][q] = wr2*vxr - wi2*vxi + cc*vyr;
                            Vi[k][q] = wr2*vxi + wi2*vxr + cc*vyi;
                        }
                        #pragma unroll
                        for (int k = 0; k < 5; ++k) {
                            float xr = Ar[p][k], xi2 = Ai[p][k];
                            float yr = Ar[q][k], yi = Ai[q][k];
                            Ar[p][k] = cc*xr - (wr2*yr - wi2*yi);
                            Ai[p][k] = cc*xi2 - (wr2*yi + wi2*yr);
                            Ar[q][k] = wr2*xr + wi2*xi2 + cc*yr;
                            Ai[q][k] = wr2*xi2 - wi2*xr + cc*yi;
                        }
                    }
                }
            }
        }
        float sv[5], s0 = 0.f;
        #pragma unroll
        for (int k = 0; k < 5; ++k) { sv[k] = sqrtf(fmaxf(Ar[k][k], 0.f)); s0 = fmaxf(s0, sv[k]); }
        float th = fmaxf(thres[b], 0.f) * s0;
        float ratio[5];
        #pragma unroll
        for (int k = 0; k < 5; ++k)
            ratio[k] = sv[k] > 0.f ? fmaxf(sv[k] - th, 0.f) / sv[k] : 0.f;
        #pragma unroll
        for (int a = 0; a < 5; ++a)
            #pragma unroll
            for (int c = 0; c < 5; ++c) {
                float wr = 0.f, wi = 0.f;
                #pragma unroll
                for (int k = 0; k < 5; ++k) {
                    wr += ratio[k] * (Vr[a][k]*Vr[c][k] + Vi[a][k]*Vi[c][k]);
                    wi += ratio[k] * (Vi[a][k]*Vr[c][k] - Vr[a][k]*Vi[c][k]);
                }
                sW[b*50 + (a*5+c)*2]   = wr;
                sW[b*50 + (a*5+c)*2+1] = wi;
            }
    }
    __syncthreads();
    for (int it = tid; it < 245*25; it += 128) {
        int blk = it / 25, e = it % 25;
        int chunk = blk / 49;
        int rem = blk % 49;
        int rx = rem / 7, ry = rem % 7;
        int i0 = rx >> 1, i1 = (rx + 1) >> 1;
        int j0 = ry >> 1, j1 = (ry + 1) >> 1;
        float sr = 0.f, si = 0.f; int cnt = 0;
        for (int i = i0; i <= i1; ++i)
            for (int j = j0; j <= j1; ++j) {
                int b = chunk*16 + i*4 + j;
                sr += sW[b*50 + e*2];
                si += sW[b*50 + e*2 + 1];
                ++cnt;
            }
        float inv = 1.f / (float)cnt;
        gA[blk*50 + e*2]   = sr * inv;
        gA[blk*50 + e*2+1] = si * inv;
    }
}

// ---------------- K3: conv pipeline. conv1 = VALU pk_fma_f16 (known-good);
// conv2+conv3 = MFMA 16x16x16_f16 on the matrix pipe, fp32 accumulate.
// p-part -> s_pout (LDS); final per-thread epilogue adds q-part; out written once.
__global__ __launch_bounds__(256, 4) void k_work(
    const float* __restrict__ re, const float* __restrict__ im,
    const unsigned int* __restrict__ wt1h, const uint2v* __restrict__ wt2m,
    const unsigned int* __restrict__ wbh,
    const float* __restrict__ w3r, const float* __restrict__ w3i,
    const float* __restrict__ b3r,
    const float* __restrict__ b2re, const float* __restrict__ b2im,
    const float* __restrict__ tau_w, const float* __restrict__ p_w,
    const int* __restrict__ num_iter,
    const float* __restrict__ gA,
    float* __restrict__ out)
{
    __shared__ unsigned int s_inv[2][12*36];                 // fp16 (re,im) input tile
    __shared__ __attribute__((aligned(16))) _Float16 h_lds[4][3][64*24 + 16];
    __shared__ unsigned int s_x5[CH][TH*TW];                 // own-pixel fp16 (re,im)
    __shared__ float s_pout[CH][TH*TW];                      // p-part per pixel

    const int tid = threadIdx.x;
    const int tx = tid & 31;
    const int ty = tid >> 5;
    const int wv = tid >> 6;          // wave id (0..3)
    const int lane = tid & 63;
    const int nn = lane & 15;         // MFMA n / row-group index
    const int hq = lane >> 4;         // MFMA k-quad / row-block index
    const int Y0 = blockIdx.x * TW;
    const int X0 = blockIdx.y * TH;
    const int z  = blockIdx.z;
    const int z0 = z * CH;
    const int fs = (z == 0) ? 0 : z0 - 1;
    const int fe = (z0 + CH < NT) ? z0 + CH : NT - 1;

    // conv1 bias (SGPR path)
    unsigned int ub1[12];
    #pragma unroll
    for (int c = 0; c < 12; ++c) ub1[c] = wbh[c];

    const float b3v = b3r[0];
    const float pw_raw = p_w[0];
    const float tsc = fmaxf(tau_w[0], 0.f) / (float)num_iter[0];
    const float pwv = fmaxf(pw_raw, 0.f);
    const float qwv = 1.f - pw_raw;

    // per-lane conv3 factors and conv2 bias by D-column
    const float fac0 = (nn < 12) ? w3r[nn] : -w3i[nn - 12];
    const float fac1 = (nn < 8)  ? -w3i[nn + 4] : 0.f;
    const float bi0  = (nn < 12) ? b2re[nn] : b2im[nn - 12];
    const float bi1  = (nn < 8)  ? b2im[nn + 4] : 0.f;

    // conv2 B-fragments: persistent VGPRs (loaded once, L2-hot)
    uint2v B2f[3][2][2];
    #pragma unroll
    for (int d = 0; d < 3; ++d)
        #pragma unroll
        for (int hf = 0; hf < 2; ++hf)
            #pragma unroll
            for (int u = 0; u < 2; ++u)
                B2f[d][hf][u] = wt2m[((d*2 + hf)*2 + u)*64 + lane];

    // staging geometry
    const int idx1 = tid + 256;
    int r0 = tid / 36, c0 = tid - r0*36;
    int gx0 = X0 + r0 - 2, gy0 = Y0 + c0 - 2;
    bool k0 = (gx0 >= 0) && (gx0 < NXY) && (gy0 >= 0) && (gy0 < NXY);
    const int a0 = (k0 ? gx0 : 0) * NXY + (k0 ? gy0 : 0);
    const float m0 = k0 ? 1.f : 0.f;
    const bool ctr0 = (r0 >= 2) && (c0 >= 2) && (c0 < 34);
    const int cadr0 = (r0-2)*TW + (c0-2);
    int r1 = idx1 / 36, c1_ = idx1 - r1*36;
    int gx1 = X0 + r1 - 2, gy1 = Y0 + c1_ - 2;
    bool k1 = (gx1 >= 0) && (gx1 < NXY) && (gy1 >= 0) && (gy1 < NXY);
    const int a1 = (k1 ? gx1 : 0) * NXY + (k1 ? gy1 : 0);
    const float m1 = k1 ? 1.f : 0.f;
    const bool ctr1 = (r1 < 10) && (c1_ >= 2) && (c1_ < 34);
    const int cadr1 = (r1-2)*TW + (c1_-2);

    // conv1 for frame tf -> relu -> h ring slot tf%3
    auto conv1_to = [&](int tf) {
        unsigned int a[12];
        #pragma unroll
        for (int c = 0; c < 12; ++c) a[c] = ub1[c];
        const unsigned int* sin_ = s_inv[tf & 1];
        #pragma unroll 1
        for (int ky = 0; ky < 5; ++ky) {
            const unsigned int* irow = &sin_[(ty+ky)*36 + tx];
            const unsigned int* wrow = &wt1h[ky*5*12];
            #pragma unroll
            for (int kx = 0; kx < 5; ++kx) {
                unsigned int x = irow[kx];
                const unsigned int* wp = wrow + kx*12;
                #pragma unroll
                for (int c = 0; c < 12; ++c) {
                    unsigned int w = wp[c];
                    CMACH(a[c], x, w);
                }
            }
        }
        unsigned int hs[12];
        #pragma unroll
        for (int c = 0; c < 12; ++c) { PKRELU(hs[c], a[c]); }
        _Float16* hb = &h_lds[wv][tf % 3][lane * 24];
        ((uint4v*)hb)[0] = uint4v{hs[0], hs[1], hs[2],  hs[3]};
        ((uint4v*)hb)[1] = uint4v{hs[4], hs[5], hs[6],  hs[7]};
        ((uint4v*)hb)[2] = uint4v{hs[8], hs[9], hs[10], hs[11]};
    };

    // conv2 (MFMA) + conv3 (reduce) + p-part for output frame tc
    auto do_out = [&](int tc, bool hasP, bool hasN) {
        const int sP = (tc + 2) % 3, sC = tc % 3, sN = (tc + 1) % 3;
        f32x4 acc[4][2];
        #pragma unroll
        for (int m = 0; m < 4; ++m) {
            acc[m][0] = f32x4{bi0, bi0, bi0, bi0};
            acc[m][1] = f32x4{bi1, bi1, bi1, bi1};
        }
        #pragma unroll
        for (int m = 0; m < 4; ++m) {
            #pragma unroll
            for (int d = 0; d < 3; ++d) {
                if (d == 0 && !hasP) continue;
                if (d == 2 && !hasN) continue;
                const int slot = (d == 0) ? sP : ((d == 1) ? sC : sN);
                #pragma unroll
                for (int hf = 0; hf < 2; ++hf) {
                    uint2v af = *(const uint2v*)
                        &h_lds[wv][slot][(16*m + nn)*24 + 16*hf + 4*hq];
                    MFMA16(acc[m][0], af, B2f[d][hf][0]);
                    MFMA16(acc[m][1], af, B2f[d][hf][1]);
                }
            }
        }
        const int fr = tc - z0;
        #pragma unroll
        for (int m = 0; m < 4; ++m) {
            float v0_ = fmaxf(acc[m][0][0], 0.f)*fac0 + fmaxf(acc[m][1][0], 0.f)*fac1;
            float v1_ = fmaxf(acc[m][0][1], 0.f)*fac0 + fmaxf(acc[m][1][1], 0.f)*fac1;
            float v2_ = fmaxf(acc[m][0][2], 0.f)*fac0 + fmaxf(acc[m][1][2], 0.f)*fac1;
            float v3_ = fmaxf(acc[m][0][3], 0.f)*fac0 + fmaxf(acc[m][1][3], 0.f)*fac1;
            #pragma unroll
            for (int mask = 1; mask <= 8; mask <<= 1) {
                v0_ += __shfl_xor(v0_, mask, 64);
                v1_ += __shfl_xor(v1_, mask, 64);
                v2_ += __shfl_xor(v2_, mask, 64);
                v3_ += __shfl_xor(v3_, mask, 64);
            }
            #pragma unroll
            for (int r = 0; r < 4; ++r) {
                float vr = (r == 0) ? v0_ : (r == 1) ? v1_ : (r == 2) ? v2_ : v3_;
                if (nn == r) {
                    int pl = wv*64 + 16*m + 4*hq + r;
                    __half2 hx = __builtin_bit_cast(__half2, s_x5[fr][pl]);
                    float reval = __low2float(hx);
                    s_pout[fr][pl] = (reval - (vr + b3v)*tsc) * pwv;
                }
            }
        }
    };

    // prologue: stage frame fs
    {
        const float* rp = re + (size_t)fs * NPIX;
        const float* ip = im + (size_t)fs * NPIX;
        float pr0 = rp[a0], pi0 = ip[a0];
        float pr1 = 0.f, pi1 = 0.f;
        if (idx1 < 432) { pr1 = rp[a1]; pi1 = ip[a1]; }
        unsigned int* dst = s_inv[fs & 1];
        unsigned int v0 = packh2f(pr0*m0, pi0*m0);
        dst[tid] = v0;
        unsigned int v1 = 0u;
        if (idx1 < 432) { v1 = packh2f(pr1*m1, pi1*m1); dst[idx1] = v1; }
        int fr = fs - z0;
        if (fr >= 0 && fr < CH) {
            if (ctr0) s_x5[fr][cadr0] = v0;
            if (idx1 < 432 && ctr1) s_x5[fr][cadr1] = v1;
        }
    }
    __syncthreads();

    #pragma unroll 1
    for (int f = fs; f <= fe; ++f) {
        float pr0 = 0.f, pi0 = 0.f, pr1 = 0.f, pi1 = 0.f;
        const bool more = (f < fe);
        if (more) {
            const float* rp = re + (size_t)(f+1) * NPIX;
            const float* ip = im + (size_t)(f+1) * NPIX;
            pr0 = rp[a0]; pi0 = ip[a0];
            if (idx1 < 432) { pr1 = rp[a1]; pi1 = ip[a1]; }
        }
        conv1_to(f);
        const int tc = f - 1;
        if (f > fs && tc >= z0)
            do_out(tc, tc >= 1, true);
        if (more) {
            unsigned int* dst = s_inv[(f+1) & 1];
            unsigned int v0 = packh2f(pr0*m0, pi0*m0);
            dst[tid] = v0;
            unsigned int v1 = 0u;
            if (idx1 < 432) { v1 = packh2f(pr1*m1, pi1*m1); dst[idx1] = v1; }
            int fr = (f + 1) - z0;
            if (fr >= 0 && fr < CH) {
                if (ctr0) s_x5[fr][cadr0] = v0;
                if (idx1 < 432 && ctr1) s_x5[fr][cadr1] = v1;
            }
        }
        __syncthreads();
    }
    if (fe == NT - 1)
        do_out(NT - 1, true, false);

    // ---- final epilogue: out = p-part + Re(Wavg . x5)*(1-p_w), one store per px
    __syncthreads();
    {
        const int X = X0 + ty, Y = Y0 + tx;
        int i_lo = (X - 4) / SXY; if (i_lo < 0) i_lo = 0;
        int i_hi = X / SXY;       if (i_hi > 3) i_hi = 3;
        int j_lo = (Y - 4) / SXY; if (j_lo < 0) j_lo = 0;
        int j_hi = Y / SXY;       if (j_hi > 3) j_hi = 3;
        const float* wa = gA + (size_t)(z*49 + (i_lo + i_hi)*7 + (j_lo + j_hi)) * 50;
        float xr5[5], xi5[5];
        #pragma unroll
        for (int r = 0; r < 5; ++r) {
            __half2 hx = __builtin_bit_cast(__half2, s_x5[r][tid]);
            xr5[r] = __low2float(hx); xi5[r] = __high2float(hx);
        }
        #pragma unroll
        for (int tl = 0; tl < 5; ++tl) {
            float qr = 0.f;
            #pragma unroll
            for (int r = 0; r < 5; ++r)
                qr += wa[(tl*5+r)*2] * xr5[r] - wa[(tl*5+r)*2+1] * xi5[r];
            out[(size_t)(z0 + tl)*NPIX + (size_t)X*NXY + Y] = s_pout[tl][tid] + qr * qwv;
        }
    }
}

extern "C" void kernel_launch(void* const* d_in, const int* in_sizes, int n_in,
                              void* d_out, int out_size, void* d_ws, size_t ws_size,
                              hipStream_t stream)
{
    const float* re    = (const float*)d_in[0];
    const float* im    = (const float*)d_in[1];
    const float* w1r   = (const float*)d_in[2];
    const float* w1i   = (const float*)d_in[3];
    const float* b1r   = (const float*)d_in[4];
    const float* b1i   = (const float*)d_in[5];
    const float* w2r   = (const float*)d_in[6];
    const float* w2i   = (const float*)d_in[7];
    const float* b2r   = (const float*)d_in[8];
    const float* b2i   = (const float*)d_in[9];
    const float* w3r   = (const float*)d_in[10];
    const float* w3i   = (const float*)d_in[11];
    const float* b3r   = (const float*)d_in[12];
    const float* thres = (const float*)d_in[14];
    const float* tau_w = (const float*)d_in[15];
    const float* p_w   = (const float*)d_in[16];
    const int* num_iter= (const int*)d_in[17];

    float* ws = (float*)d_ws;
    unsigned int* wt1h = (unsigned int*)ws;          // 300 uints (pad 512)
    unsigned int* wbh  = wt1h + 512;                 // 12 uints (pad 64)
    unsigned int* wt2m = wbh + 64;                   // 768 uint2 = 1536 uints
    float* gP  = (float*)(wt2m + 1536);              // 80*GSL*50 floats
    float* gA  = gP + 80*GSL*50;                     // 245*50 floats

    float* outf = (float*)d_out;

    k_pre<<<648, 256, 0, stream>>>(re, im, w1r, w1i, w2r, w2i, b1r, b1i,
                                   wt1h, wbh, wt2m, gP);
    k_post<<<1, 128, 0, stream>>>(gP, thres, gA);
    dim3 g1(NXY/TW, NXY/TH, NZ);
    k_work<<<g1, 256, 0, stream>>>(re, im, wt1h, (const uint2v*)wt2m, wbh,
                                   w3r, w3i, b3r, b2r, b2i,
                                   tau_w, p_w, num_iter, gA, outf);
}

// Round 13
// 388.849 us; speedup vs baseline: 1.1919x; 1.0272x over previous
//
#include <hip/hip_runtime.h>
#include <hip/hip_fp16.h>

#define NT 25
#define NXY 448
#define NPIX (448*448)
#define PXY 115
#define SXY 111

#define TW 32
#define TH 8
#define CH 5          // output frames per time-chunk
#define NZ 5          // number of time chunks (NT/CH)
#define GSL 8         // gram spatial slices

typedef float f32x4 __attribute__((ext_vector_type(4)));
typedef __fp16 f16x4 __attribute__((ext_vector_type(4)));
typedef unsigned int uint2v __attribute__((ext_vector_type(2)));

// MFMA 16x16x16 f16 via INTRINSIC (not inline asm): compiler inserts the required
// MFMA hazard waits and schedules the region — r11's inline-asm version produced inf,
// prime suspect being untracked VALU->MFMA operand hazards in the dense conv1 region.
// Layout convention (HW-verified by r10's conv2 pass):
// A: lane l holds A[l%16][4*(l/16)+j]; B: lane l holds B[4*(l/16)+j][l%16];
// D: lane l holds D[4*(l/16)+j][l%16].
#define MFMA16(acc, a, b)                                                                          \
    acc = __builtin_amdgcn_mfma_f32_16x16x16f16((a), (b), (acc), 0, 0, 0)

static __device__ __forceinline__ unsigned int packh2f(float lo, float hi) {
    auto h = __builtin_amdgcn_cvt_pkrtz(lo, hi);
    return __builtin_bit_cast(unsigned int, h);
}

// ---------------- K1: gram partials (gid<640) + MFMA weight packing (gid>=640)
// wt1m: conv1 im2col B-fragments, frag (kk,u) for K=64: k = 2*tap + ri (rows k>=50
//       ZERO), n interleaved (n=2c re, 2c+1 im), cols n>=24 ZERO.
// wt2m: conv2 B-fragments, frag (d,hf,u): K=24 interleaved input (rows>=24 zero),
//       N=24 legacy order [re0..11, im0..11] (r10-verified).
__global__ __launch_bounds__(256) void k_pre(
    const float* __restrict__ re, const float* __restrict__ im,
    const float* __restrict__ w1r, const float* __restrict__ w1i,
    const float* __restrict__ w2r, const float* __restrict__ w2i,
    unsigned int* __restrict__ wt1m, unsigned int* __restrict__ wt2m,
    float* __restrict__ gP)
{
    const int gid = blockIdx.x;
    const int tid = threadIdx.x;

    if (gid >= 640) {
        int i = (gid - 640) * 256 + tid;
        if (i < 512) {              // conv1 B-frags: 8 frags (kk 0..3, u 0..1) x 64 lanes
            int l = i & 63; int t = i >> 6;
            int u = t & 1, kk = t >> 1;
            unsigned short us[4];
            #pragma unroll
            for (int j = 0; j < 4; ++j) {
                int k = 16*kk + 4*(l >> 4) + j;
                int n = 16*u + (l & 15);
                float v = 0.f;
                if (k < 50 && n < 24) {
                    int tap = k >> 1; int ri = k & 1;
                    int c = n >> 1;  int rc = n & 1;
                    float wre = w1r[c*25 + tap];
                    float wim = w1i[c*25 + tap];
                    v = (ri == 0) ? (rc == 0 ? wre : wim) : (rc == 0 ? -wim : wre);
                }
                us[j] = __half_as_ushort(__float2half_rn(v));
            }
            wt1m[i*2]   = (unsigned int)us[0] | ((unsigned int)us[1] << 16);
            wt1m[i*2+1] = (unsigned int)us[2] | ((unsigned int)us[3] << 16);
        }
        if (i < 768) {              // conv2 B-frags: 12 frags (d,hf,u) x 64 lanes
            int l = i & 63; int t = i >> 6;
            int u = t & 1, hf = (t >> 1) & 1, d = t >> 2;
            unsigned short us[4];
            #pragma unroll
            for (int j = 0; j < 4; ++j) {
                int k = 16*hf + 4*(l >> 4) + j;
                int n = 16*u + (l & 15);
                float v = 0.f;
                if (k < 24 && n < 24) {
                    int cin = k >> 1; bool imin = (k & 1) != 0;
                    int cout = (n < 12) ? n : n - 12; bool reout = n < 12;
                    float wre = w2r[(cout*12 + cin)*3 + d];
                    float wim = w2i[(cout*12 + cin)*3 + d];
                    v = !imin ? (reout ? wre : wim) : (reout ? -wim : wre);
                }
                us[j] = __half_as_ushort(__float2half_rn(v));
            }
            wt2m[i*2]   = (unsigned int)us[0] | ((unsigned int)us[1] << 16);
            wt2m[i*2+1] = (unsigned int)us[2] | ((unsigned int)us[3] << 16);
        }
        return;
    }

    // ---- gram path (unchanged) ----
    __shared__ float s_red[4][50];
    const int b = gid >> 3;
    const int slice = gid & 7;
    const int chunk = b >> 4;
    const int pidx = b & 15;
    const int X0 = (pidx >> 2) * SXY;
    const int Y0 = (pidx & 3) * SXY;

    float acc[50];
    #pragma unroll
    for (int k = 0; k < 50; ++k) acc[k] = 0.f;

    const int npx = PXY * PXY;
    for (int pi = slice*256 + tid; pi < npx; pi += 256*GSL) {
        int px = pi / PXY, py = pi % PXY;
        size_t base = (size_t)(X0 + px) * NXY + (Y0 + py);
        float xr[5], xi[5];
        #pragma unroll
        for (int r = 0; r < 5; ++r) {
            size_t a = (size_t)(chunk*5 + r) * NPIX + base;
            xr[r] = re[a]; xi[r] = im[a];
        }
        #pragma unroll
        for (int t1 = 0; t1 < 5; ++t1)
            #pragma unroll
            for (int t2 = 0; t2 < 5; ++t2) {
                acc[(t1*5+t2)*2]   += xr[t1]*xr[t2] + xi[t1]*xi[t2];
                acc[(t1*5+t2)*2+1] += xi[t1]*xr[t2] - xr[t1]*xi[t2];
            }
    }
    #pragma unroll
    for (int k = 0; k < 50; ++k) {
        float v = acc[k];
        for (int m = 32; m > 0; m >>= 1) v += __shfl_xor(v, m, 64);
        acc[k] = v;
    }
    int lane = tid & 63, wid = tid >> 6;
    if (lane == 0) {
        #pragma unroll
        for (int k = 0; k < 50; ++k) s_red[wid][k] = acc[k];
    }
    __syncthreads();
    if (tid < 50) {
        gP[(b*GSL + slice)*50 + tid] =
            s_red[0][tid] + s_red[1][tid] + s_red[2][tid] + s_red[3][tid];
    }
}

// ---------------- K2: fold Gram partials -> Jacobi eig -> W (LDS) -> region-avg gA
__global__ __launch_bounds__(128) void k_post(
    const float* __restrict__ gP, const float* __restrict__ thres,
    float* __restrict__ gA)
{
    __shared__ float sW[80*50];
    const int tid = threadIdx.x;
    if (tid < 80) {
        const int b = tid;
        float Ar[5][5], Ai[5][5], Vr[5][5], Vi[5][5];
        #pragma unroll
        for (int a = 0; a < 5; ++a)
            #pragma unroll
            for (int c = 0; c < 5; ++c) {
                float sr = 0.f, si = 0.f;
                #pragma unroll
                for (int sl = 0; sl < GSL; ++sl) {
                    sr += gP[(b*GSL + sl)*50 + (a*5+c)*2];
                    si += gP[(b*GSL + sl)*50 + (a*5+c)*2 + 1];
                }
                Ar[a][c] = sr; Ai[a][c] = si;
                Vr[a][c] = (a==c) ? 1.f : 0.f;
                Vi[a][c] = 0.f;
            }
        for (int sw = 0; sw < 9; ++sw) {
            #pragma unroll
            for (int p = 0; p < 4; ++p) {
                #pragma unroll
                for (int q = p+1; q < 5; ++q) {
                    float apr = Ar[p][q], api = Ai[p][q];
                    float n2 = apr*apr + api*api;
                    if (n2 > 1e-24f) {
                        float mlen = sqrtf(n2);
                        float phr = apr / mlen, phi = api / mlen;
                        float tau = (Ar[q][q] - Ar[p][p]) / (2.f * mlen);
                        float tt = (tau >= 0.f ? 1.f : -1.f) / (fabsf(tau) + sqrtf(1.f + tau*tau));
                        float cc = 1.f / sqrtf(1.f + tt*tt);
                        float ss = tt * cc;
                        float wr2 = ss * phr, wi2 = ss * phi;
                        #pragma unroll
                        for (int k = 0; k < 5; ++k) {
                            float xr = Ar[k][p], xi2 = Ai[k][p];
                            float yr = Ar[k][q], yi = Ai[k][q];
                            Ar[k][p] = cc*xr - (wr2*yr + wi2*yi);
                            Ai[k][p] = cc*xi2 - (wr2*yi - wi2*yr);
                            Ar[k][q] = wr2*xr - wi2*xi2 + cc*yr;
                            Ai[k][q] = wr2*xi2 + wi2*xr + cc*yi;
                            float vxr = Vr[k][p], vxi = Vi[k][p];
                            float vyr = Vr[k][q], vyi = Vi[k][q];
                            Vr[k][p] = cc*vxr - (wr2*vyr + wi2*vyi);
                            Vi[k][p] = cc*vxi - (wr2*vyi - wi2*vyr);
                            Vr[k][q] = wr2*vxr - wi2*vxi + cc*vyr;
                            Vi[k][q] = wr2*vxi + wi2*vxr + cc*vyi;
                        }
                        #pragma unroll
                        for (int k = 0; k < 5; ++k) {
                            float xr = Ar[p][k], xi2 = Ai[p][k];
                            float yr = Ar[q][k], yi = Ai[q][k];
                            Ar[p][k] = cc*xr - (wr2*yr - wi2*yi);
                            Ai[p][k] = cc*xi2 - (wr2*yi + wi2*yr);
                            Ar[q][k] = wr2*xr + wi2*xi2 + cc*yr;
                            Ai[q][k] = wr2*xi2 - wi2*xr + cc*yi;
                        }
                    }
                }
            }
        }
        float sv[5], s0 = 0.f;
        #pragma unroll
        for (int k = 0; k < 5; ++k) { sv[k] = sqrtf(fmaxf(Ar[k][k], 0.f)); s0 = fmaxf(s0, sv[k]); }
        float th = fmaxf(thres[b], 0.f) * s0;
        float ratio[5];
        #pragma unroll
        for (int k = 0; k < 5; ++k)
            ratio[k] = sv[k] > 0.f ? fmaxf(sv[k] - th, 0.f) / sv[k] : 0.f;
        #pragma unroll
        for (int a = 0; a < 5; ++a)
            #pragma unroll
            for (int c = 0; c < 5; ++c) {
                float wr = 0.f, wi = 0.f;
                #pragma unroll
                for (int k = 0; k < 5; ++k) {
                    wr += ratio[k] * (Vr[a][k]*Vr[c][k] + Vi[a][k]*Vi[c][k]);
                    wi += ratio[k] * (Vi[a][k]*Vr[c][k] - Vr[a][k]*Vi[c][k]);
                }
                sW[b*50 + (a*5+c)*2]   = wr;
                sW[b*50 + (a*5+c)*2+1] = wi;
            }
    }
    __syncthreads();
    for (int it = tid; it < 245*25; it += 128) {
        int blk = it / 25, e = it % 25;
        int chunk = blk / 49;
        int rem = blk % 49;
        int rx = rem / 7, ry = rem % 7;
        int i0 = rx >> 1, i1 = (rx + 1) >> 1;
        int j0 = ry >> 1, j1 = (ry + 1) >> 1;
        float sr = 0.f, si = 0.f; int cnt = 0;
        for (int i = i0; i <= i1; ++i)
            for (int j = j0; j <= j1; ++j) {
                int b = chunk*16 + i*4 + j;
                sr += sW[b*50 + e*2];
                si += sW[b*50 + e*2 + 1];
                ++cnt;
            }
        float inv = 1.f / (float)cnt;
        gA[blk*50 + e*2]   = sr * inv;
        gA[blk*50 + e*2+1] = si * inv;
    }
}

// ---------------- K3: full-MFMA conv pipeline (intrinsic MFMAs).
// conv1: im2col MFMA from s_inv (A rows = pixels 16m+nn, k = 2*tap+ri, K=64
//        zero-padded in B), fp32 accum + bias, relu, f16 store to h ring.
// conv2: MFMA from h ring (r10-verified). conv3: per-lane factor + shfl reduce.
// Final epilogue adds low-rank q-part; out written exactly once.
__global__ __launch_bounds__(256, 4) void k_work(
    const float* __restrict__ re, const float* __restrict__ im,
    const f16x4* __restrict__ wt1m, const f16x4* __restrict__ wt2m,
    const float* __restrict__ b1re, const float* __restrict__ b1im,
    const float* __restrict__ w3r, const float* __restrict__ w3i,
    const float* __restrict__ b3r,
    const float* __restrict__ b2re, const float* __restrict__ b2im,
    const float* __restrict__ tau_w, const float* __restrict__ p_w,
    const int* __restrict__ num_iter,
    const float* __restrict__ gA,
    float* __restrict__ out)
{
    __shared__ unsigned int s_inv[2][12*36];                 // fp16 (re,im) input tile
    __shared__ __attribute__((aligned(16))) _Float16 h_lds[4][3][64*24 + 16];
    __shared__ unsigned int s_x5[CH][TH*TW];                 // own-pixel fp16 (re,im)
    __shared__ float s_pout[CH][TH*TW];                      // p-part per pixel

    const int tid = threadIdx.x;
    const int wv = tid >> 6;          // wave id (0..3)
    const int lane = tid & 63;
    const int nn = lane & 15;
    const int hq = lane >> 4;
    const int Y0 = blockIdx.x * TW;
    const int X0 = blockIdx.y * TH;
    const int z  = blockIdx.z;
    const int z0 = z * CH;
    const int fs = (z == 0) ? 0 : z0 - 1;
    const int fe = (z0 + CH < NT) ? z0 + CH : NT - 1;

    const float b3v = b3r[0];
    const float pw_raw = p_w[0];
    const float tsc = fmaxf(tau_w[0], 0.f) / (float)num_iter[0];
    const float pwv = fmaxf(pw_raw, 0.f);
    const float qwv = 1.f - pw_raw;

    // conv3 factors / conv2 bias by D-column (n = nn for u0, 16+nn for u1)
    const float fac0 = (nn < 12) ? w3r[nn] : -w3i[nn - 12];
    const float fac1 = (nn < 8)  ? -w3i[nn + 4] : 0.f;
    const float bi0  = (nn < 12) ? b2re[nn] : b2im[nn - 12];
    const float bi1  = (nn < 8)  ? b2im[nn + 4] : 0.f;
    // conv1 bias by D-column (interleaved n-order: n=2c+rc)
    const float b1c0 = (nn & 1) ? b1im[nn >> 1] : b1re[nn >> 1];
    const float b1c1 = (nn < 8) ? ((nn & 1) ? b1im[8 + (nn >> 1)] : b1re[8 + (nn >> 1)]) : 0.f;

    // conv1 per-lane tap offsets into s_inv: k-quad 4hq of k-step kk covers taps
    // t0=8kk+2hq and t1=t0+1; taps >24 clamp to 24 (their B rows k>=50 are ZERO)
    int off0[4], off1[4];
    #pragma unroll
    for (int kk = 0; kk < 4; ++kk) {
        int t0 = 8*kk + 2*hq; if (t0 > 24) t0 = 24;
        int t1 = 8*kk + 2*hq + 1; if (t1 > 24) t1 = 24;
        off0[kk] = (t0 / 5) * 36 + (t0 % 5);
        off1[kk] = (t1 / 5) * 36 + (t1 % 5);
    }

    // B fragments resident in VGPRs (loaded once, L2-hot)
    f16x4 B1f[4][2];
    #pragma unroll
    for (int kk = 0; kk < 4; ++kk)
        #pragma unroll
        for (int u = 0; u < 2; ++u)
            B1f[kk][u] = wt1m[(kk*2 + u)*64 + lane];
    f16x4 B2f[3][2][2];
    #pragma unroll
    for (int d = 0; d < 3; ++d)
        #pragma unroll
        for (int hf = 0; hf < 2; ++hf)
            #pragma unroll
            for (int u = 0; u < 2; ++u)
                B2f[d][hf][u] = wt2m[((d*2 + hf)*2 + u)*64 + lane];

    // staging geometry
    const int idx1 = tid + 256;
    int r0 = tid / 36, c0 = tid - r0*36;
    int gx0 = X0 + r0 - 2, gy0 = Y0 + c0 - 2;
    bool k0 = (gx0 >= 0) && (gx0 < NXY) && (gy0 >= 0) && (gy0 < NXY);
    const int a0 = (k0 ? gx0 : 0) * NXY + (k0 ? gy0 : 0);
    const float m0 = k0 ? 1.f : 0.f;
    const bool ctr0 = (r0 >= 2) && (c0 >= 2) && (c0 < 34);
    const int cadr0 = (r0-2)*TW + (c0-2);
    int r1 = idx1 / 36, c1_ = idx1 - r1*36;
    int gx1 = X0 + r1 - 2, gy1 = Y0 + c1_ - 2;
    bool k1 = (gx1 >= 0) && (gx1 < NXY) && (gy1 >= 0) && (gy1 < NXY);
    const int a1 = (k1 ? gx1 : 0) * NXY + (k1 ? gy1 : 0);
    const float m1 = k1 ? 1.f : 0.f;
    const bool ctr1 = (r1 < 10) && (c1_ >= 2) && (c1_ < 34);
    const int cadr1 = (r1-2)*TW + (c1_-2);

    // conv1 (MFMA) for frame tf -> relu -> h ring slot tf%3
    auto conv1_to = [&](int tf) {
        const unsigned int* sin_ = s_inv[tf & 1];
        f32x4 acc1[4][2];
        #pragma unroll
        for (int m = 0; m < 4; ++m) {
            acc1[m][0] = f32x4{b1c0, b1c0, b1c0, b1c0};
            acc1[m][1] = f32x4{b1c1, b1c1, b1c1, b1c1};
        }
        #pragma unroll
        for (int m = 0; m < 4; ++m) {
            const int pb = (2*wv + (m >> 1))*36 + 16*(m & 1) + nn;
            #pragma unroll
            for (int kk = 0; kk < 4; ++kk) {
                uint2v au;
                au.x = sin_[pb + off0[kk]];
                au.y = sin_[pb + off1[kk]];
                f16x4 af = __builtin_bit_cast(f16x4, au);
                MFMA16(acc1[m][0], af, B1f[kk][0]);
                MFMA16(acc1[m][1], af, B1f[kk][1]);
            }
        }
        _Float16* hb = &h_lds[wv][tf % 3][0];
        #pragma unroll
        for (int m = 0; m < 4; ++m)
            #pragma unroll
            for (int j = 0; j < 4; ++j) {
                const int px = 16*m + 4*hq + j;
                hb[px*24 + nn] = (_Float16)fmaxf(acc1[m][0][j], 0.f);
                if (nn < 8)
                    hb[px*24 + 16 + nn] = (_Float16)fmaxf(acc1[m][1][j], 0.f);
            }
    };

    // conv2 (MFMA) + conv3 (reduce) + p-part for output frame tc
    auto do_out = [&](int tc, bool hasP, bool hasN) {
        const int sP = (tc + 2) % 3, sC = tc % 3, sN = (tc + 1) % 3;
        f32x4 acc[4][2];
        #pragma unroll
        for (int m = 0; m < 4; ++m) {
            acc[m][0] = f32x4{bi0, bi0, bi0, bi0};
            acc[m][1] = f32x4{bi1, bi1, bi1, bi1};
        }
        #pragma unroll
        for (int m = 0; m < 4; ++m) {
            #pragma unroll
            for (int d = 0; d < 3; ++d) {
                if (d == 0 && !hasP) continue;
                if (d == 2 && !hasN) continue;
                const int slot = (d == 0) ? sP : ((d == 1) ? sC : sN);
                #pragma unroll
                for (int hf = 0; hf < 2; ++hf) {
                    f16x4 af = *(const f16x4*)
                        &h_lds[wv][slot][(16*m + nn)*24 + 16*hf + 4*hq];
                    MFMA16(acc[m][0], af, B2f[d][hf][0]);
                    MFMA16(acc[m][1], af, B2f[d][hf][1]);
                }
            }
        }
        const int fr = tc - z0;
        #pragma unroll
        for (int m = 0; m < 4; ++m) {
            float v0_ = fmaxf(acc[m][0][0], 0.f)*fac0 + fmaxf(acc[m][1][0], 0.f)*fac1;
            float v1_ = fmaxf(acc[m][0][1], 0.f)*fac0 + fmaxf(acc[m][1][1], 0.f)*fac1;
            float v2_ = fmaxf(acc[m][0][2], 0.f)*fac0 + fmaxf(acc[m][1][2], 0.f)*fac1;
            float v3_ = fmaxf(acc[m][0][3], 0.f)*fac0 + fmaxf(acc[m][1][3], 0.f)*fac1;
            #pragma unroll
            for (int mask = 1; mask <= 8; mask <<= 1) {
                v0_ += __shfl_xor(v0_, mask, 64);
                v1_ += __shfl_xor(v1_, mask, 64);
                v2_ += __shfl_xor(v2_, mask, 64);
                v3_ += __shfl_xor(v3_, mask, 64);
            }
            #pragma unroll
            for (int r = 0; r < 4; ++r) {
                float vr = (r == 0) ? v0_ : (r == 1) ? v1_ : (r == 2) ? v2_ : v3_;
                if (nn == r) {
                    int pl = wv*64 + 16*m + 4*hq + r;
                    __half2 hx = __builtin_bit_cast(__half2, s_x5[fr][pl]);
                    float reval = __low2float(hx);
                    s_pout[fr][pl] = (reval - (vr + b3v)*tsc) * pwv;
                }
            }
        }
    };

    // prologue: stage frame fs
    {
        const float* rp = re + (size_t)fs * NPIX;
        const float* ip = im + (size_t)fs * NPIX;
        float pr0 = rp[a0], pi0 = ip[a0];
        float pr1 = 0.f, pi1 = 0.f;
        if (idx1 < 432) { pr1 = rp[a1]; pi1 = ip[a1]; }
        unsigned int* dst = s_inv[fs & 1];
        unsigned int v0 = packh2f(pr0*m0, pi0*m0);
        dst[tid] = v0;
        unsigned int v1 = 0u;
        if (idx1 < 432) { v1 = packh2f(pr1*m1, pi1*m1); dst[idx1] = v1; }
        int fr = fs - z0;
        if (fr >= 0 && fr < CH) {
            if (ctr0) s_x5[fr][cadr0] = v0;
            if (idx1 < 432 && ctr1) s_x5[fr][cadr1] = v1;
        }
    }
    __syncthreads();

    #pragma unroll 1
    for (int f = fs; f <= fe; ++f) {
        float pr0 = 0.f, pi0 = 0.f, pr1 = 0.f, pi1 = 0.f;
        const bool more = (f < fe);
        if (more) {
            const float* rp = re + (size_t)(f+1) * NPIX;
            const float* ip = im + (size_t)(f+1) * NPIX;
            pr0 = rp[a0]; pi0 = ip[a0];
            if (idx1 < 432) { pr1 = rp[a1]; pi1 = ip[a1]; }
        }
        conv1_to(f);
        const int tc = f - 1;
        if (f > fs && tc >= z0)
            do_out(tc, tc >= 1, true);
        if (more) {
            unsigned int* dst = s_inv[(f+1) & 1];
            unsigned int v0 = packh2f(pr0*m0, pi0*m0);
            dst[tid] = v0;
            unsigned int v1 = 0u;
            if (idx1 < 432) { v1 = packh2f(pr1*m1, pi1*m1); dst[idx1] = v1; }
            int fr = (f + 1) - z0;
            if (fr >= 0 && fr < CH) {
                if (ctr0) s_x5[fr][cadr0] = v0;
                if (idx1 < 432 && ctr1) s_x5[fr][cadr1] = v1;
            }
        }
        __syncthreads();
    }
    if (fe == NT - 1)
        do_out(NT - 1, true, false);

    // ---- final epilogue: out = p-part + Re(Wavg . x5)*(1-p_w), one store per px
    __syncthreads();
    {
        const int tx = tid & 31, ty = tid >> 5;
        const int X = X0 + ty, Y = Y0 + tx;
        int i_lo = (X - 4) / SXY; if (i_lo < 0) i_lo = 0;
        int i_hi = X / SXY;       if (i_hi > 3) i_hi = 3;
        int j_lo = (Y - 4) / SXY; if (j_lo < 0) j_lo = 0;
        int j_hi = Y / SXY;       if (j_hi > 3) j_hi = 3;
        const float* wa = gA + (size_t)(z*49 + (i_lo + i_hi)*7 + (j_lo + j_hi)) * 50;
        float xr5[5], xi5[5];
        #pragma unroll
        for (int r = 0; r < 5; ++r) {
            __half2 hx = __builtin_bit_cast(__half2, s_x5[r][tid]);
            xr5[r] = __low2float(hx); xi5[r] = __high2float(hx);
        }
        #pragma unroll
        for (int tl = 0; tl < 5; ++tl) {
            float qr = 0.f;
            #pragma unroll
            for (int r = 0; r < 5; ++r)
                qr += wa[(tl*5+r)*2] * xr5[r] - wa[(tl*5+r)*2+1] * xi5[r];
            out[(size_t)(z0 + tl)*NPIX + (size_t)X*NXY + Y] = s_pout[tl][tid] + qr * qwv;
        }
    }
}

extern "C" void kernel_launch(void* const* d_in, const int* in_sizes, int n_in,
                              void* d_out, int out_size, void* d_ws, size_t ws_size,
                              hipStream_t stream)
{
    const float* re    = (const float*)d_in[0];
    const float* im    = (const float*)d_in[1];
    const float* w1r   = (const float*)d_in[2];
    const float* w1i   = (const float*)d_in[3];
    const float* b1r   = (const float*)d_in[4];
    const float* b1i   = (const float*)d_in[5];
    const float* w2r   = (const float*)d_in[6];
    const float* w2i   = (const float*)d_in[7];
    const float* b2r   = (const float*)d_in[8];
    const float* b2i   = (const float*)d_in[9];
    const float* w3r   = (const float*)d_in[10];
    const float* w3i   = (const float*)d_in[11];
    const float* b3r   = (const float*)d_in[12];
    const float* thres = (const float*)d_in[14];
    const float* tau_w = (const float*)d_in[15];
    const float* p_w   = (const float*)d_in[16];
    const int* num_iter= (const int*)d_in[17];

    float* ws = (float*)d_ws;
    unsigned int* wt1m = (unsigned int*)ws;          // 1024 uints (512 f16x4 frags)
    unsigned int* wt2m = wt1m + 1024;                // 1536 uints (768 f16x4 frags)
    float* gP  = (float*)(wt2m + 1536);              // 80*GSL*50 floats
    float* gA  = gP + 80*GSL*50;                     // 245*50 floats

    float* outf = (float*)d_out;

    k_pre<<<648, 256, 0, stream>>>(re, im, w1r, w1i, w2r, w2i, wt1m, wt2m, gP);
    k_post<<<1, 128, 0, stream>>>(gP, thres, gA);
    dim3 g1(NXY/TW, NXY/TH, NZ);
    k_work<<<g1, 256, 0, stream>>>(re, im, (const f16x4*)wt1m, (const f16x4*)wt2m,
                                   b1r, b1i, w3r, w3i, b3r, b2r, b2i,
                                   tau_w, p_w, num_iter, gA, outf);
}

// Round 14
// 299.489 us; speedup vs baseline: 1.5476x; 1.2984x over previous
//
#include <hip/hip_runtime.h>
#include <hip/hip_fp16.h>

#define NT 25
#define NXY 448
#define NPIX (448*448)
#define PXY 115
#define SXY 111

#define TW 32
#define TH 8
#define CH 5          // output frames per time-chunk
#define NZ 5          // number of time chunks (NT/CH)
#define GSL 8         // gram spatial slices

typedef float f32x4 __attribute__((ext_vector_type(4)));
typedef __fp16 f16x4 __attribute__((ext_vector_type(4)));
typedef unsigned int uint2v __attribute__((ext_vector_type(2)));

// MFMA 16x16x16 f16 intrinsic. Layout (HW-verified r10/r13):
// A: lane l holds A[l%16][4*(l/16)+j]; B: lane l holds B[4*(l/16)+j][l%16];
// D: lane l holds D[4*(l/16)+j][l%16].
// TRANSPOSED CHAIN: conv1 computes h^T = W1^T (A) x x^T (B); its D fragment
// (rows 4hq+j = h-channel, col nn = pixel) IS conv2's B fragment (rows k = h-channel,
// col = pixel) -> h stays in REGISTERS, no LDS round-trip.
#define MFMA16(acc, a, b)                                                                          \
    acc = __builtin_amdgcn_mfma_f32_16x16x16f16((a), (b), (acc), 0, 0, 0)

static __device__ __forceinline__ unsigned int packh2f(float lo, float hi) {
    auto h = __builtin_amdgcn_cvt_pkrtz(lo, hi);
    return __builtin_bit_cast(unsigned int, h);
}

// ---------------- K1: gram partials (gid<640) + MFMA weight packing (gid>=640)
// Transposed fragments, n interleaved (n = 2c + rc; rc: 0=re,1=im):
// wt1m: A=W1^T frags (nf,kk): lane l elem j = W1^T[n1=nn+16nf][k1=16kk+4hq+j],
//       k1 = 2*tap+ri (rows k1>=50 zero, cols n1>=24 zero).
// wt2m: A=W2^T frags (d,nf,kf): lane l elem j = W2^T[n2=nn+16nf][k=16kf+4hq+j],
//       k = 2*cin+ri (zero outside 24x24).
// value rule: v = ri==0 ? (rc==0? wr : wi) : (rc==0? -wi : wr)
__global__ __launch_bounds__(256) void k_pre(
    const float* __restrict__ re, const float* __restrict__ im,
    const float* __restrict__ w1r, const float* __restrict__ w1i,
    const float* __restrict__ w2r, const float* __restrict__ w2i,
    unsigned int* __restrict__ wt1m, unsigned int* __restrict__ wt2m,
    float* __restrict__ gP)
{
    const int gid = blockIdx.x;
    const int tid = threadIdx.x;

    if (gid >= 640) {
        int i = (gid - 640) * 256 + tid;
        int l = i & 63; int t = i >> 6;
        int nn = l & 15, hq = l >> 4;
        if (i < 512) {              // conv1: 8 frags, t = nf*4 + kk
            int kk = t & 3, nf = t >> 2;
            unsigned short us[4];
            #pragma unroll
            for (int j = 0; j < 4; ++j) {
                int n1 = nn + 16*nf;
                int k1 = 16*kk + 4*hq + j;
                float v = 0.f;
                if (k1 < 50 && n1 < 24) {
                    int tap = k1 >> 1; int ri = k1 & 1;
                    int c = n1 >> 1;  int rc = n1 & 1;
                    float wre = w1r[c*25 + tap];
                    float wim = w1i[c*25 + tap];
                    v = (ri == 0) ? (rc == 0 ? wre : wim) : (rc == 0 ? -wim : wre);
                }
                us[j] = __half_as_ushort(__float2half_rn(v));
            }
            wt1m[i*2]   = (unsigned int)us[0] | ((unsigned int)us[1] << 16);
            wt1m[i*2+1] = (unsigned int)us[2] | ((unsigned int)us[3] << 16);
        }
        if (i < 768) {              // conv2: 12 frags, t = d*4 + nf*2 + kf
            int kf = t & 1, nf = (t >> 1) & 1, d = t >> 2;
            unsigned short us[4];
            #pragma unroll
            for (int j = 0; j < 4; ++j) {
                int n2 = nn + 16*nf;
                int k = 16*kf + 4*hq + j;
                float v = 0.f;
                if (k < 24 && n2 < 24) {
                    int cin = k >> 1; int ri = k & 1;
                    int cout = n2 >> 1; int rc = n2 & 1;
                    float wre = w2r[(cout*12 + cin)*3 + d];
                    float wim = w2i[(cout*12 + cin)*3 + d];
                    v = (ri == 0) ? (rc == 0 ? wre : wim) : (rc == 0 ? -wim : wre);
                }
                us[j] = __half_as_ushort(__float2half_rn(v));
            }
            wt2m[i*2]   = (unsigned int)us[0] | ((unsigned int)us[1] << 16);
            wt2m[i*2+1] = (unsigned int)us[2] | ((unsigned int)us[3] << 16);
        }
        return;
    }

    // ---- gram path (unchanged) ----
    __shared__ float s_red[4][50];
    const int b = gid >> 3;
    const int slice = gid & 7;
    const int chunk = b >> 4;
    const int pidx = b & 15;
    const int X0 = (pidx >> 2) * SXY;
    const int Y0 = (pidx & 3) * SXY;

    float acc[50];
    #pragma unroll
    for (int k = 0; k < 50; ++k) acc[k] = 0.f;

    const int npx = PXY * PXY;
    for (int pi = slice*256 + tid; pi < npx; pi += 256*GSL) {
        int px = pi / PXY, py = pi % PXY;
        size_t base = (size_t)(X0 + px) * NXY + (Y0 + py);
        float xr[5], xi[5];
        #pragma unroll
        for (int r = 0; r < 5; ++r) {
            size_t a = (size_t)(chunk*5 + r) * NPIX + base;
            xr[r] = re[a]; xi[r] = im[a];
        }
        #pragma unroll
        for (int t1 = 0; t1 < 5; ++t1)
            #pragma unroll
            for (int t2 = 0; t2 < 5; ++t2) {
                acc[(t1*5+t2)*2]   += xr[t1]*xr[t2] + xi[t1]*xi[t2];
                acc[(t1*5+t2)*2+1] += xi[t1]*xr[t2] - xr[t1]*xi[t2];
            }
    }
    #pragma unroll
    for (int k = 0; k < 50; ++k) {
        float v = acc[k];
        for (int m = 32; m > 0; m >>= 1) v += __shfl_xor(v, m, 64);
        acc[k] = v;
    }
    int lane = tid & 63, wid = tid >> 6;
    if (lane == 0) {
        #pragma unroll
        for (int k = 0; k < 50; ++k) s_red[wid][k] = acc[k];
    }
    __syncthreads();
    if (tid < 50) {
        gP[(b*GSL + slice)*50 + tid] =
            s_red[0][tid] + s_red[1][tid] + s_red[2][tid] + s_red[3][tid];
    }
}

// ---------------- K2: fold Gram partials -> Jacobi eig -> W (LDS) -> region-avg gA
__global__ __launch_bounds__(128) void k_post(
    const float* __restrict__ gP, const float* __restrict__ thres,
    float* __restrict__ gA)
{
    __shared__ float sW[80*50];
    const int tid = threadIdx.x;
    if (tid < 80) {
        const int b = tid;
        float Ar[5][5], Ai[5][5], Vr[5][5], Vi[5][5];
        #pragma unroll
        for (int a = 0; a < 5; ++a)
            #pragma unroll
            for (int c = 0; c < 5; ++c) {
                float sr = 0.f, si = 0.f;
                #pragma unroll
                for (int sl = 0; sl < GSL; ++sl) {
                    sr += gP[(b*GSL + sl)*50 + (a*5+c)*2];
                    si += gP[(b*GSL + sl)*50 + (a*5+c)*2 + 1];
                }
                Ar[a][c] = sr; Ai[a][c] = si;
                Vr[a][c] = (a==c) ? 1.f : 0.f;
                Vi[a][c] = 0.f;
            }
        for (int sw = 0; sw < 9; ++sw) {
            #pragma unroll
            for (int p = 0; p < 4; ++p) {
                #pragma unroll
                for (int q = p+1; q < 5; ++q) {
                    float apr = Ar[p][q], api = Ai[p][q];
                    float n2 = apr*apr + api*api;
                    if (n2 > 1e-24f) {
                        float mlen = sqrtf(n2);
                        float phr = apr / mlen, phi = api / mlen;
                        float tau = (Ar[q][q] - Ar[p][p]) / (2.f * mlen);
                        float tt = (tau >= 0.f ? 1.f : -1.f) / (fabsf(tau) + sqrtf(1.f + tau*tau));
                        float cc = 1.f / sqrtf(1.f + tt*tt);
                        float ss = tt * cc;
                        float wr2 = ss * phr, wi2 = ss * phi;
                        #pragma unroll
                        for (int k = 0; k < 5; ++k) {
                            float xr = Ar[k][p], xi2 = Ai[k][p];
                            float yr = Ar[k][q], yi = Ai[k][q];
                            Ar[k][p] = cc*xr - (wr2*yr + wi2*yi);
                            Ai[k][p] = cc*xi2 - (wr2*yi - wi2*yr);
                            Ar[k][q] = wr2*xr - wi2*xi2 + cc*yr;
                            Ai[k][q] = wr2*xi2 + wi2*xr + cc*yi;
                            float vxr = Vr[k][p], vxi = Vi[k][p];
                            float vyr = Vr[k][q], vyi = Vi[k][q];
                            Vr[k][p] = cc*vxr - (wr2*vyr + wi2*vyi);
                            Vi[k][p] = cc*vxi - (wr2*vyi - wi2*vyr);
                            Vr[k][q] = wr2*vxr - wi2*vxi + cc*vyr;
                            Vi[k][q] = wr2*vxi + wi2*vxr + cc*vyi;
                        }
                        #pragma unroll
                        for (int k = 0; k < 5; ++k) {
                            float xr = Ar[p][k], xi2 = Ai[p][k];
                            float yr = Ar[q][k], yi = Ai[q][k];
                            Ar[p][k] = cc*xr - (wr2*yr - wi2*yi);
                            Ai[p][k] = cc*xi2 - (wr2*yi + wi2*yr);
                            Ar[q][k] = wr2*xr + wi2*xi2 + cc*yr;
                            Ai[q][k] = wr2*xi2 - wi2*xr + cc*yi;
                        }
                    }
                }
            }
        }
        float sv[5], s0 = 0.f;
        #pragma unroll
        for (int k = 0; k < 5; ++k) { sv[k] = sqrtf(fmaxf(Ar[k][k], 0.f)); s0 = fmaxf(s0, sv[k]); }
        float th = fmaxf(thres[b], 0.f) * s0;
        float ratio[5];
        #pragma unroll
        for (int k = 0; k < 5; ++k)
            ratio[k] = sv[k] > 0.f ? fmaxf(sv[k] - th, 0.f) / sv[k] : 0.f;
        #pragma unroll
        for (int a = 0; a < 5; ++a)
            #pragma unroll
            for (int c = 0; c < 5; ++c) {
                float wr = 0.f, wi = 0.f;
                #pragma unroll
                for (int k = 0; k < 5; ++k) {
                    wr += ratio[k] * (Vr[a][k]*Vr[c][k] + Vi[a][k]*Vi[c][k]);
                    wi += ratio[k] * (Vi[a][k]*Vr[c][k] - Vr[a][k]*Vi[c][k]);
                }
                sW[b*50 + (a*5+c)*2]   = wr;
                sW[b*50 + (a*5+c)*2+1] = wi;
            }
    }
    __syncthreads();
    for (int it = tid; it < 245*25; it += 128) {
        int blk = it / 25, e = it % 25;
        int chunk = blk / 49;
        int rem = blk % 49;
        int rx = rem / 7, ry = rem % 7;
        int i0 = rx >> 1, i1 = (rx + 1) >> 1;
        int j0 = ry >> 1, j1 = (ry + 1) >> 1;
        float sr = 0.f, si = 0.f; int cnt = 0;
        for (int i = i0; i <= i1; ++i)
            for (int j = j0; j <= j1; ++j) {
                int b = chunk*16 + i*4 + j;
                sr += sW[b*50 + e*2];
                si += sW[b*50 + e*2 + 1];
                ++cnt;
            }
        float inv = 1.f / (float)cnt;
        gA[blk*50 + e*2]   = sr * inv;
        gA[blk*50 + e*2+1] = si * inv;
    }
}

// ---------------- K3: register-resident transposed-MFMA conv pipeline.
// conv1: h^T = W1^T x x^T, D frags = conv2 B frags -> h in registers (3 frames).
// conv2: z^T = W2^T x h^T (A2 streamed per-d from L2). conv3: per-lane fac + 2 shfl.
// No h LDS. Final epilogue adds low-rank q-part; out written exactly once.
__global__ __launch_bounds__(256, 3) void k_work(
    const float* __restrict__ re, const float* __restrict__ im,
    const f16x4* __restrict__ wt1m, const f16x4* __restrict__ wt2m,
    const float* __restrict__ b1re, const float* __restrict__ b1im,
    const float* __restrict__ w3r, const float* __restrict__ w3i,
    const float* __restrict__ b3r,
    const float* __restrict__ b2re, const float* __restrict__ b2im,
    const float* __restrict__ tau_w, const float* __restrict__ p_w,
    const int* __restrict__ num_iter,
    const float* __restrict__ gA,
    float* __restrict__ out)
{
    __shared__ unsigned int s_inv[2][12*36];                 // fp16 (re,im) input tile
    __shared__ unsigned int s_x5[CH][TH*TW];                 // own-pixel fp16 (re,im)
    __shared__ float s_pout[CH][TH*TW];                      // p-part per pixel

    const int tid = threadIdx.x;
    const int wv = tid >> 6;          // wave id (0..3)
    const int lane = tid & 63;
    const int nn = lane & 15;
    const int hq = lane >> 4;
    const int Y0 = blockIdx.x * TW;
    const int X0 = blockIdx.y * TH;
    const int z  = blockIdx.z;
    const int z0 = z * CH;
    const int fs = (z == 0) ? 0 : z0 - 1;
    const int fe = (z0 + CH < NT) ? z0 + CH : NT - 1;

    const float b3v = b3r[0];
    const float pw_raw = p_w[0];
    const float tsc = fmaxf(tau_w[0], 0.f) / (float)num_iter[0];
    const float pwv = fmaxf(pw_raw, 0.f);
    const float qwv = 1.f - pw_raw;

    // per-lane bias/fac by D-row n = 16nf + 4hq + j (interleaved n = 2c+rc)
    f32x4 b1A, b1B, b2A, b2B, facA, facB;
    #pragma unroll
    for (int j = 0; j < 4; ++j) {
        int n = 4*hq + j;                      // nf=0: always <16 valid
        int c = n >> 1, rc = n & 1;
        b1A[j]  = rc ? b1im[c] : b1re[c];
        b2A[j]  = rc ? b2im[c] : b2re[c];
        facA[j] = rc ? -w3i[c] : w3r[c];
        int n2 = 16 + 4*hq + j;                // nf=1: valid only n2<24
        if (n2 < 24) {
            int c2 = n2 >> 1, rc2 = n2 & 1;
            b1B[j]  = rc2 ? b1im[c2] : b1re[c2];
            b2B[j]  = rc2 ? b2im[c2] : b2re[c2];
            facB[j] = rc2 ? -w3i[c2] : w3r[c2];
        } else {
            b1B[j] = 0.f; b2B[j] = 0.f; facB[j] = 0.f;
        }
    }

    // conv1 per-lane tap offsets (IDENTICAL to r13's verified gather)
    int off0[4], off1[4];
    #pragma unroll
    for (int kk = 0; kk < 4; ++kk) {
        int t0 = 8*kk + 2*hq; if (t0 > 24) t0 = 24;
        int t1 = 8*kk + 2*hq + 1; if (t1 > 24) t1 = 24;
        off0[kk] = (t0 / 5) * 36 + (t0 % 5);
        off1[kk] = (t1 / 5) * 36 + (t1 % 5);
    }

    // conv1 A fragments resident (used every frame)
    f16x4 A1f[2][4];
    #pragma unroll
    for (int nf = 0; nf < 2; ++nf)
        #pragma unroll
        for (int kk = 0; kk < 4; ++kk)
            A1f[nf][kk] = wt1m[(nf*4 + kk)*64 + lane];

    // staging geometry
    const int idx1 = tid + 256;
    int r0 = tid / 36, c0 = tid - r0*36;
    int gx0 = X0 + r0 - 2, gy0 = Y0 + c0 - 2;
    bool k0 = (gx0 >= 0) && (gx0 < NXY) && (gy0 >= 0) && (gy0 < NXY);
    const int a0 = (k0 ? gx0 : 0) * NXY + (k0 ? gy0 : 0);
    const float m0 = k0 ? 1.f : 0.f;
    const bool ctr0 = (r0 >= 2) && (c0 >= 2) && (c0 < 34);
    const int cadr0 = (r0-2)*TW + (c0-2);
    int r1 = idx1 / 36, c1_ = idx1 - r1*36;
    int gx1 = X0 + r1 - 2, gy1 = Y0 + c1_ - 2;
    bool k1 = (gx1 >= 0) && (gx1 < NXY) && (gy1 >= 0) && (gy1 < NXY);
    const int a1 = (k1 ? gx1 : 0) * NXY + (k1 ? gy1 : 0);
    const float m1 = k1 ? 1.f : 0.f;
    const bool ctr1 = (r1 < 10) && (c1_ >= 2) && (c1_ < 34);
    const int cadr1 = (r1-2)*TW + (c1_-2);

    // h state: 3 frames x 4 m' x 2 kf fragments (f16x4) in REGISTERS
    f16x4 hA[4][2], hB[4][2], hC[4][2];
    #pragma unroll
    for (int m = 0; m < 4; ++m)
        #pragma unroll
        for (int kf = 0; kf < 2; ++kf) {
            hA[m][kf] = f16x4{0,0,0,0}; hB[m][kf] = f16x4{0,0,0,0}; hC[m][kf] = f16x4{0,0,0,0};
        }

    // conv1 (transposed MFMA) for frame tf -> relu -> hC register fragments
    auto conv1_to = [&](int tf) {
        const unsigned int* sin_ = s_inv[tf & 1];
        #pragma unroll
        for (int m = 0; m < 4; ++m) {
            f32x4 acc0 = b1A, acc1 = b1B;
            const int pb = (2*wv + (m >> 1))*36 + 16*(m & 1) + nn;
            #pragma unroll
            for (int kk = 0; kk < 4; ++kk) {
                uint2v au;
                au.x = sin_[pb + off0[kk]];
                au.y = sin_[pb + off1[kk]];
                f16x4 bf = __builtin_bit_cast(f16x4, au);
                MFMA16(acc0, A1f[0][kk], bf);
                MFMA16(acc1, A1f[1][kk], bf);
            }
            uint2v h0, h1;
            h0.x = packh2f(fmaxf(acc0[0],0.f), fmaxf(acc0[1],0.f));
            h0.y = packh2f(fmaxf(acc0[2],0.f), fmaxf(acc0[3],0.f));
            h1.x = packh2f(fmaxf(acc1[0],0.f), fmaxf(acc1[1],0.f));
            h1.y = packh2f(fmaxf(acc1[2],0.f), fmaxf(acc1[3],0.f));
            hC[m][0] = __builtin_bit_cast(f16x4, h0);
            hC[m][1] = __builtin_bit_cast(f16x4, h1);
        }
    };

    // conv2 (transposed MFMA, A2 streamed) + conv3 + p-part for output frame tc
    auto do_out = [&](int tc, bool hasP, bool hasN) {
        f32x4 acc[4][2];
        #pragma unroll
        for (int m = 0; m < 4; ++m) { acc[m][0] = b2A; acc[m][1] = b2B; }
        #pragma unroll
        for (int d = 0; d < 3; ++d) {
            if (d == 0 && !hasP) continue;
            if (d == 2 && !hasN) continue;
            f16x4 a2[2][2];
            #pragma unroll
            for (int nf = 0; nf < 2; ++nf)
                #pragma unroll
                for (int kf = 0; kf < 2; ++kf)
                    a2[nf][kf] = wt2m[(d*4 + nf*2 + kf)*64 + lane];
            const f16x4 (*hs)[2] = (d == 0) ? hA : ((d == 1) ? hB : hC);
            #pragma unroll
            for (int m = 0; m < 4; ++m) {
                #pragma unroll
                for (int kf = 0; kf < 2; ++kf) {
                    MFMA16(acc[m][0], a2[0][kf], hs[m][kf]);
                    MFMA16(acc[m][1], a2[1][kf], hs[m][kf]);
                }
            }
        }
        const int fr = tc - z0;
        #pragma unroll
        for (int m = 0; m < 4; ++m) {
            float s = 0.f;
            #pragma unroll
            for (int j = 0; j < 4; ++j)
                s += fmaxf(acc[m][0][j], 0.f)*facA[j] + fmaxf(acc[m][1][j], 0.f)*facB[j];
            s += __shfl_xor(s, 16, 64);
            s += __shfl_xor(s, 32, 64);
            if (hq == 0) {
                int pl = wv*64 + 16*m + nn;
                __half2 hx = __builtin_bit_cast(__half2, s_x5[fr][pl]);
                float reval = __low2float(hx);
                s_pout[fr][pl] = (reval - (s + b3v)*tsc) * pwv;
            }
        }
    };

    // prologue: stage frame fs
    {
        const float* rp = re + (size_t)fs * NPIX;
        const float* ip = im + (size_t)fs * NPIX;
        float pr0 = rp[a0], pi0 = ip[a0];
        float pr1 = 0.f, pi1 = 0.f;
        if (idx1 < 432) { pr1 = rp[a1]; pi1 = ip[a1]; }
        unsigned int* dst = s_inv[fs & 1];
        unsigned int v0 = packh2f(pr0*m0, pi0*m0);
        dst[tid] = v0;
        unsigned int v1 = 0u;
        if (idx1 < 432) { v1 = packh2f(pr1*m1, pi1*m1); dst[idx1] = v1; }
        int fr = fs - z0;
        if (fr >= 0 && fr < CH) {
            if (ctr0) s_x5[fr][cadr0] = v0;
            if (idx1 < 432 && ctr1) s_x5[fr][cadr1] = v1;
        }
    }
    __syncthreads();

    #pragma unroll 1
    for (int f = fs; f <= fe; ++f) {
        float pr0 = 0.f, pi0 = 0.f, pr1 = 0.f, pi1 = 0.f;
        const bool more = (f < fe);
        if (more) {
            const float* rp = re + (size_t)(f+1) * NPIX;
            const float* ip = im + (size_t)(f+1) * NPIX;
            pr0 = rp[a0]; pi0 = ip[a0];
            if (idx1 < 432) { pr1 = rp[a1]; pi1 = ip[a1]; }
        }
        conv1_to(f);
        const int tc = f - 1;
        if (f > fs && tc >= z0)
            do_out(tc, tc >= 1, true);
        if (more) {
            unsigned int* dst = s_inv[(f+1) & 1];
            unsigned int v0 = packh2f(pr0*m0, pi0*m0);
            dst[tid] = v0;
            unsigned int v1 = 0u;
            if (idx1 < 432) { v1 = packh2f(pr1*m1, pi1*m1); dst[idx1] = v1; }
            int fr = (f + 1) - z0;
            if (fr >= 0 && fr < CH) {
                if (ctr0) s_x5[fr][cadr0] = v0;
                if (idx1 < 432 && ctr1) s_x5[fr][cadr1] = v1;
            }
        }
        __syncthreads();
        #pragma unroll
        for (int m = 0; m < 4; ++m)
            #pragma unroll
            for (int kf = 0; kf < 2; ++kf) {
                hA[m][kf] = hB[m][kf];
                hB[m][kf] = hC[m][kf];
            }
    }
    if (fe == NT - 1) {
        // after the last rotation: hA=h[23], hB=h[24]; do_out reads hB via d=1 and
        // hA via d=0; hC (stale h[24... ]) is masked by hasN=false.
        do_out(NT - 1, true, false);
    }

    // ---- final epilogue: out = p-part + Re(Wavg . x5)*(1-p_w), one store per px
    __syncthreads();
    {
        const int tx = tid & 31, ty = tid >> 5;
        const int X = X0 + ty, Y = Y0 + tx;
        int i_lo = (X - 4) / SXY; if (i_lo < 0) i_lo = 0;
        int i_hi = X / SXY;       if (i_hi > 3) i_hi = 3;
        int j_lo = (Y - 4) / SXY; if (j_lo < 0) j_lo = 0;
        int j_hi = Y / SXY;       if (j_hi > 3) j_hi = 3;
        const float* wa = gA + (size_t)(z*49 + (i_lo + i_hi)*7 + (j_lo + j_hi)) * 50;
        float xr5[5], xi5[5];
        #pragma unroll
        for (int r = 0; r < 5; ++r) {
            __half2 hx = __builtin_bit_cast(__half2, s_x5[r][tid]);
            xr5[r] = __low2float(hx); xi5[r] = __high2float(hx);
        }
        #pragma unroll
        for (int tl = 0; tl < 5; ++tl) {
            float qr = 0.f;
            #pragma unroll
            for (int r = 0; r < 5; ++r)
                qr += wa[(tl*5+r)*2] * xr5[r] - wa[(tl*5+r)*2+1] * xi5[r];
            out[(size_t)(z0 + tl)*NPIX + (size_t)X*NXY + Y] = s_pout[tl][tid] + qr * qwv;
        }
    }
}

extern "C" void kernel_launch(void* const* d_in, const int* in_sizes, int n_in,
                              void* d_out, int out_size, void* d_ws, size_t ws_size,
                              hipStream_t stream)
{
    const float* re    = (const float*)d_in[0];
    const float* im    = (const float*)d_in[1];
    const float* w1r   = (const float*)d_in[2];
    const float* w1i   = (const float*)d_in[3];
    const float* b1r   = (const float*)d_in[4];
    const float* b1i   = (const float*)d_in[5];
    const float* w2r   = (const float*)d_in[6];
    const float* w2i   = (const float*)d_in[7];
    const float* b2r   = (const float*)d_in[8];
    const float* b2i   = (const float*)d_in[9];
    const float* w3r   = (const float*)d_in[10];
    const float* w3i   = (const float*)d_in[11];
    const float* b3r   = (const float*)d_in[12];
    const float* thres = (const float*)d_in[14];
    const float* tau_w = (const float*)d_in[15];
    const float* p_w   = (const float*)d_in[16];
    const int* num_iter= (const int*)d_in[17];

    float* ws = (float*)d_ws;
    unsigned int* wt1m = (unsigned int*)ws;          // 1024 uints (512 f16x4 frags)
    unsigned int* wt2m = wt1m + 1024;                // 1536 uints (768 f16x4 frags)
    float* gP  = (float*)(wt2m + 1536);              // 80*GSL*50 floats
    float* gA  = gP + 80*GSL*50;                     // 245*50 floats

    float* outf = (float*)d_out;

    k_pre<<<648, 256, 0, stream>>>(re, im, w1r, w1i, w2r, w2i, wt1m, wt2m, gP);
    k_post<<<1, 128, 0, stream>>>(gP, thres, gA);
    dim3 g1(NXY/TW, NXY/TH, NZ);
    k_work<<<g1, 256, 0, stream>>>(re, im, (const f16x4*)wt1m, (const f16x4*)wt2m,
                                   b1r, b1i, w3r, w3i, b3r, b2r, b2i,
                                   tau_w, p_w, num_iter, gA, outf);
}